// Round 1
// baseline (7446.116 us; speedup 1.0000x reference)
//
#include <hip/hip_runtime.h>

#define B 4
#define S 128
#define D 1024
#define NS 4
#define KF 8
#define LNUM 3
#define DFF 3072
#define ND 4096
#define T 1024          // S*KF
#define VOCABSZ 6144
#define SINKIT 20

// ---------------- sinkhorn + softmax(w_pre/w_post) -> params block ----------------
__global__ void sink_kernel(const float* __restrict__ Hl, const float* __restrict__ wpre,
                            const float* __restrict__ wpost, float* __restrict__ prm) {
  if (threadIdx.x != 0 || blockIdx.x != 0) return;
  float M[16];
  for (int i = 0; i < 16; ++i) M[i] = expf(Hl[i]);
  for (int it = 0; it < SINKIT; ++it) {
    for (int m = 0; m < 4; ++m) {
      float s = M[m*4+0] + M[m*4+1] + M[m*4+2] + M[m*4+3];
      for (int n = 0; n < 4; ++n) M[m*4+n] /= s;
    }
    for (int n = 0; n < 4; ++n) {
      float s = M[0*4+n] + M[1*4+n] + M[2*4+n] + M[3*4+n];
      for (int m = 0; m < 4; ++m) M[m*4+n] /= s;
    }
  }
  for (int i = 0; i < 16; ++i) prm[i] = M[i];
  float a[4], mx, sm;
  mx = fmaxf(fmaxf(wpre[0], wpre[1]), fmaxf(wpre[2], wpre[3]));
  sm = 0.f; for (int i = 0; i < 4; ++i) { a[i] = expf(wpre[i] - mx); sm += a[i]; }
  for (int i = 0; i < 4; ++i) prm[16+i] = a[i] / sm;
  mx = fmaxf(fmaxf(wpost[0], wpost[1]), fmaxf(wpost[2], wpost[3]));
  sm = 0.f; for (int i = 0; i < 4; ++i) { a[i] = expf(wpost[i] - mx); sm += a[i]; }
  for (int i = 0; i < 4; ++i) prm[20+i] = a[i] / sm;
}

// ---------------- layer-0 h init: broadcast embedding over streams ----------------
__global__ __launch_bounds__(256)
void gather_kernel(const int* __restrict__ tok, const float* __restrict__ embed,
                   float* __restrict__ h) {
  const int idx = blockIdx.x * 256 + threadIdx.x;   // over S*B*NS*D
  const int d   = idx % D;
  const int sbn = idx / D;
  const int sb  = sbn / NS;
  const int b   = sb % B, s = sb / B;
  h[idx] = embed[(size_t)tok[b*S + s] * D + d];
}

// ---------------- h_mix = H @ h (streams), x = softmax(w_pre) . h_mix ----------------
__global__ __launch_bounds__(256)
void mix_kernel(const float* __restrict__ h, const float* __restrict__ P,
                float* __restrict__ h_mix, float* __restrict__ x) {
  const int idx = blockIdx.x * 256 + threadIdx.x;   // over S*B*D
  const int d = idx % D, sb = idx / D;
  const float* hp = h + (size_t)sb * NS * D + d;
  const float h0 = hp[0], h1 = hp[D], h2 = hp[2*D], h3 = hp[3*D];
  float xv = 0.f;
  #pragma unroll
  for (int m = 0; m < 4; ++m) {
    float hm = P[m*4+0]*h0 + P[m*4+1]*h1 + P[m*4+2]*h2 + P[m*4+3]*h3;
    h_mix[(size_t)sb * NS * D + m*D + d] = hm;
    xv = fmaf(P[16+m], hm, xv);
  }
  x[idx] = xv;
}

// ---------------- PLIF scan (serial over T, parallel over B*C) ----------------
// R1: z1 indexed by token (S,B,C) repeated K times; else full (T,B,C). A2: add z2 (T,B,C).
template<bool R1, bool A2>
__global__ __launch_bounds__(256)
void plif_kernel(const float* __restrict__ z1, const float* __restrict__ z2,
                 const float* __restrict__ beta, const float* __restrict__ vth,
                 float* __restrict__ outp, int C) {
  const int idx = blockIdx.x * 256 + threadIdx.x;   // over B*C
  const int c = idx % C;
  const int stride = B * C;
  const float be = beta[c], vt = vth[c], omb = 1.f - be;
  float v = 0.f;
  #pragma unroll 8
  for (int t = 0; t < T; ++t) {
    float xt = R1 ? z1[(size_t)(t >> 3) * stride + idx] : z1[(size_t)t * stride + idx];
    if (A2) xt += z2[(size_t)t * stride + idx];
    v = fmaf(be, v, omb * xt);
    float sc = (v >= vt) ? vt : 0.f;   // spike current = vth * spike
    v -= sc;
    outp[(size_t)t * stride + idx] = sc;
  }
}

// ---------------- fused gate+up PLIF, writes p = g*u in-place over zg ----------------
__global__ __launch_bounds__(256)
void plif_gu_kernel(float* __restrict__ zg, const float* __restrict__ zu,
                    const float* __restrict__ bg, const float* __restrict__ vg_,
                    const float* __restrict__ bu, const float* __restrict__ vu_) {
  const int idx = blockIdx.x * 256 + threadIdx.x;   // over B*DFF
  const int c = idx % DFF;
  const int stride = B * DFF;
  const float beg = bg[c], vtg = vg_[c], beu = bu[c], vtu = vu_[c];
  const float og = 1.f - beg, ou = 1.f - beu;
  float vg = 0.f, vu = 0.f;
  #pragma unroll 8
  for (int t = 0; t < T; ++t) {
    const size_t off = (size_t)t * stride + idx;
    float gi = zg[off], ui = zu[off];
    vg = fmaf(beg, vg, og * gi);
    vu = fmaf(beu, vu, ou * ui);
    float sg = (vg >= vtg) ? vtg : 0.f; vg -= sg;
    float su = (vu >= vtu) ? vtu : 0.f; vu -= su;
    zg[off] = sg * su;
  }
}

// ---------------- fp32 SGEMM: C = A(MxK) @ B(KxN) [+ Cin], BT: B given as (NxK) ----------------
// 128x128 tile, BK=8, 256 threads, 8x8 per thread (split-quadrant mapping).
template<bool BT, bool ADDC>
__global__ __launch_bounds__(256)
void sgemm_kernel(const float* __restrict__ A, const float* __restrict__ Bm,
                  const float* __restrict__ Cin, float* __restrict__ Cout,
                  int M, int N, int Kd) {
  __shared__ float As[8][128];
  __shared__ float Bs[8][128];
  const int tid = threadIdx.x;
  const int bn = blockIdx.x, bm = blockIdx.y;
  const int tx = tid & 15, ty = tid >> 4;

  const int arow = tid >> 1;
  const int akp  = (tid & 1) * 4;
  const float* Ap = A + (size_t)(bm*128 + arow) * Kd + akp;

  const float* Bp;
  int bn_row = 0, bkp = 0, bk = 0, bcol = 0;
  if (BT) {
    bn_row = tid >> 1; bkp = (tid & 1) * 4;
    Bp = Bm + (size_t)(bn*128 + bn_row) * Kd + bkp;
  } else {
    bk = tid >> 5; bcol = (tid & 31) * 4;
    Bp = Bm + (size_t)bk * N + bn*128 + bcol;
  }

  float acc[8][8];
  #pragma unroll
  for (int i = 0; i < 8; ++i)
    #pragma unroll
    for (int j = 0; j < 8; ++j) acc[i][j] = 0.f;

  for (int k0 = 0; k0 < Kd; k0 += 8) {
    const float4 av = *(const float4*)Ap; Ap += 8;
    const float4 bv = *(const float4*)Bp;
    if (BT) Bp += 8; else Bp += (size_t)8 * N;

    As[akp+0][arow] = av.x; As[akp+1][arow] = av.y;
    As[akp+2][arow] = av.z; As[akp+3][arow] = av.w;
    if (BT) {
      Bs[bkp+0][bn_row] = bv.x; Bs[bkp+1][bn_row] = bv.y;
      Bs[bkp+2][bn_row] = bv.z; Bs[bkp+3][bn_row] = bv.w;
    } else {
      *(float4*)&Bs[bk][bcol] = bv;
    }
    __syncthreads();
    #pragma unroll
    for (int k = 0; k < 8; ++k) {
      float ra[8], rb[8];
      #pragma unroll
      for (int i = 0; i < 4; ++i) { ra[i] = As[k][ty*4 + i]; ra[4+i] = As[k][64 + ty*4 + i]; }
      #pragma unroll
      for (int j = 0; j < 4; ++j) { rb[j] = Bs[k][tx*4 + j]; rb[4+j] = Bs[k][64 + tx*4 + j]; }
      #pragma unroll
      for (int i = 0; i < 8; ++i)
        #pragma unroll
        for (int j = 0; j < 8; ++j)
          acc[i][j] = fmaf(ra[i], rb[j], acc[i][j]);
    }
    __syncthreads();
  }

  #pragma unroll
  for (int ih = 0; ih < 2; ++ih) {
    #pragma unroll
    for (int i = 0; i < 4; ++i) {
      const int row = bm*128 + ih*64 + ty*4 + i;
      const int ai = ih*4 + i;
      float vals[8];
      #pragma unroll
      for (int j = 0; j < 8; ++j) vals[j] = acc[ai][j];
      float* cp = Cout + (size_t)row * N + bn*128;
      if (ADDC) {
        const float* ci = Cin + (size_t)row * N + bn*128;
        const float4 c0 = *(const float4*)(ci + tx*4);
        const float4 c1 = *(const float4*)(ci + 64 + tx*4);
        vals[0] += c0.x; vals[1] += c0.y; vals[2] += c0.z; vals[3] += c0.w;
        vals[4] += c1.x; vals[5] += c1.y; vals[6] += c1.z; vals[7] += c1.w;
      }
      *(float4*)(cp + tx*4)      = make_float4(vals[0], vals[1], vals[2], vals[3]);
      *(float4*)(cp + 64 + tx*4) = make_float4(vals[4], vals[5], vals[6], vals[7]);
    }
  }
}

// ---------------- PonderNet halting + stream write-back ----------------
__global__ __launch_bounds__(256)
void halt_kernel(const float* __restrict__ y, const float* __restrict__ h_mix,
                 const float* __restrict__ P, const float* __restrict__ hw,
                 const float* __restrict__ hb, float* __restrict__ h_out,
                 float* __restrict__ ek_acc) {
  const int sb = blockIdx.x;           // s*B + b
  const int b = sb % B, s = sb / B;
  const int tid = threadIdx.x;
  __shared__ float red[256];
  __shared__ float lam_s[KF];
  __shared__ float pk_s[KF];

  for (int k = 0; k < KF; ++k) {
    const float* yr = y + ((size_t)(s*KF + k) * B + b) * D;
    float p = 0.f;
    for (int d = tid; d < D; d += 256) p = fmaf(yr[d], hw[d], p);
    red[tid] = p; __syncthreads();
    for (int off = 128; off > 0; off >>= 1) {
      if (tid < off) red[tid] += red[tid + off];
      __syncthreads();
    }
    if (tid == 0) lam_s[k] = 1.f / (1.f + expf(-(red[0] + hb[0])));
    __syncthreads();
  }
  if (tid == 0) {
    float keep = 1.f, sum = 0.f, pk[KF];
    #pragma unroll
    for (int k = 0; k < KF; ++k) { pk[k] = lam_s[k] * keep; keep *= (1.f - lam_s[k]); sum += pk[k]; }
    pk[KF-1] += 1.f - sum;
    float ek = 0.f;
    #pragma unroll
    for (int k = 0; k < KF; ++k) { ek += pk[k] * (float)(k + 1); pk_s[k] = pk[k]; }
    atomicAdd(ek_acc, ek);
  }
  __syncthreads();
  for (int d = tid; d < D; d += 256) {
    float yt = 0.f;
    #pragma unroll
    for (int k = 0; k < KF; ++k)
      yt = fmaf(pk_s[k], y[((size_t)(s*KF + k) * B + b) * D + d], yt);
    #pragma unroll
    for (int n = 0; n < NS; ++n) {
      const size_t off = ((size_t)sb * NS + n) * D + d;
      h_out[off] = h_mix[off] + P[20+n] * yt;
    }
  }
}

// ---------------- decode: stream-collapse + rmsnorm ----------------
__global__ __launch_bounds__(256)
void collnorm_kernel(const float* __restrict__ h, const float* __restrict__ w,
                     float* __restrict__ xn) {
  const int sb = blockIdx.x, tid = threadIdx.x;
  __shared__ float red[256];
  float vals[4]; float ss = 0.f;
  #pragma unroll
  for (int i = 0; i < 4; ++i) {
    const int d = tid + i*256;
    const float* hp = h + (size_t)sb * NS * D + d;
    float m = 0.25f * (hp[0] + hp[D] + hp[2*D] + hp[3*D]);
    vals[i] = m; ss += m*m;
  }
  red[tid] = ss; __syncthreads();
  for (int off = 128; off > 0; off >>= 1) { if (tid < off) red[tid] += red[tid + off]; __syncthreads(); }
  const float inv = 1.f / sqrtf(red[0] * (1.f/(float)D) + 1e-6f);
  #pragma unroll
  for (int i = 0; i < 4; ++i) {
    const int d = tid + i*256;
    xn[(size_t)sb * D + d] = vals[i] * w[d] * inv;
  }
}

// ---------------- decode output neuron PLIF + K-frame mean, transposed write ----------------
__global__ __launch_bounds__(256)
void dplif_kernel(const float* __restrict__ xn, const float* __restrict__ beta,
                  const float* __restrict__ vth, float* __restrict__ dec) {
  const int idx = blockIdx.x * 256 + threadIdx.x;   // over B*D
  const int b = idx / D, d = idx % D;
  const float be = beta[d], vt = vth[d], omb = 1.f - be;
  float v = 0.f;
  for (int s = 0; s < S; ++s) {
    const float xv = xn[((size_t)s * B + b) * D + d];
    float acc = 0.f;
    #pragma unroll
    for (int k = 0; k < KF; ++k) {
      v = fmaf(be, v, omb * xv);
      float sc = (v >= vt) ? vt : 0.f;
      v -= sc; acc += sc;
    }
    dec[((size_t)b * S + s) * D + d] = acc * (1.f/(float)KF);
  }
}

// ---------------- lateral inhibition (in-place, with bias add) ----------------
__global__ __launch_bounds__(256)
void li_kernel(float* __restrict__ hh, const float* __restrict__ bias,
               const float* __restrict__ w) {
  const int r = blockIdx.x, tid = threadIdx.x;
  __shared__ float red[256];
  float* row = hh + (size_t)r * D;
  float v[4]; float sm = 0.f;
  #pragma unroll
  for (int i = 0; i < 4; ++i) { const int d = tid + i*256; v[i] = row[d] + bias[d]; sm += v[i]; }
  red[tid] = sm; __syncthreads();
  for (int off = 128; off > 0; off >>= 1) { if (tid < off) red[tid] += red[tid + off]; __syncthreads(); }
  const float mean = red[0] * (1.f/(float)D);
  __syncthreads();
  float ss = 0.f;
  #pragma unroll
  for (int i = 0; i < 4; ++i) { v[i] -= mean; ss += v[i]*v[i]; }
  red[tid] = ss; __syncthreads();
  for (int off = 128; off > 0; off >>= 1) { if (tid < off) red[tid] += red[tid + off]; __syncthreads(); }
  const float inv = 1.f / sqrtf(red[0] * (1.f/(float)D) + 1e-6f);
  #pragma unroll
  for (int i = 0; i < 4; ++i) { const int d = tid + i*256; row[d] = w[d] * v[i] * inv; }
}

// ---------------- ponder / ekf tail ----------------
__global__ void finalize_kernel(const float* __restrict__ ek_acc, float* __restrict__ tail) {
  if (threadIdx.x != 0 || blockIdx.x != 0) return;
  float ponder = 0.f, ekf = 0.f;
  for (int l = 0; l < LNUM; ++l) {
    float ek = ek_acc[l] * (1.f/(float)(S*B));
    ponder += ek;
    ekf += fmaxf(0.f - ek, 0.f);
  }
  tail[0] = ponder * (1.f/(float)LNUM);
  tail[1] = ekf * (1.f/(float)LNUM);
}

extern "C" void kernel_launch(void* const* d_in, const int* in_sizes, int n_in,
                              void* d_out, int out_size, void* d_ws, size_t ws_size,
                              hipStream_t stream) {
  const int*   tok       = (const int*)  d_in[0];
  const float* embed     = (const float*)d_in[1];
  const float* norm_w    = (const float*)d_in[2];
  const float* decode_W  = (const float*)d_in[3];
  const float* decode_b  = (const float*)d_in[4];
  const float* out_norm  = (const float*)d_in[5];
  const float* beta_out  = (const float*)d_in[6];
  const float* vth_out   = (const float*)d_in[7];
  const float* H_logits  = (const float*)d_in[8];
  const float* w_pre     = (const float*)d_in[9];
  const float* w_post    = (const float*)d_in[10];
  const float* beta_in1  = (const float*)d_in[11];
  const float* vth_in1   = (const float*)d_in[12];
  const float* W_in      = (const float*)d_in[13];
  const float* beta_h    = (const float*)d_in[14];
  const float* vth_h     = (const float*)d_in[15];
  const float* W_out     = (const float*)d_in[16];
  const float* beta_in2  = (const float*)d_in[17];
  const float* vth_in2   = (const float*)d_in[18];
  const float* W_gate    = (const float*)d_in[19];
  const float* beta_gate = (const float*)d_in[20];
  const float* vth_gate  = (const float*)d_in[21];
  const float* W_up      = (const float*)d_in[22];
  const float* beta_up   = (const float*)d_in[23];
  const float* vth_up    = (const float*)d_in[24];
  const float* W_down    = (const float*)d_in[25];
  const float* halt_w    = (const float*)d_in[26];
  const float* halt_b    = (const float*)d_in[27];
  float* out = (float*)d_out;

  float* ws = (float*)d_ws;
  size_t o = 0;
  float* prm   = ws + o; o += 256;                     // per-layer [H16|wpre4|wpost4] at l*32; ek at +96
  float* h_cur = ws + o; o += (size_t)S*B*NS*D;
  float* h_mix = ws + o; o += (size_t)S*B*NS*D;
  float* xbuf  = ws + o; o += (size_t)S*B*D;
  float* s1    = ws + o; o += (size_t)T*B*D;
  float* big1  = ws + o; o += (size_t)T*B*ND;          // z_h, later z_g -> p (in place)
  float* big2  = ws + o; o += (size_t)T*B*ND;          // sh,  later z_u
  float* y_blk = ws + o; o += (size_t)T*B*D;
  float* s2    = ws + o; o += (size_t)T*B*D;
  float* xn    = ws + o; o += (size_t)S*B*D;
  float* dec   = ws + o; o += (size_t)B*S*D;
  float* hh    = ws + o; o += (size_t)B*S*D;
  if (ws_size < o * sizeof(float)) return;             // fail loudly (output stays zero)

  float* ek_acc = prm + 96;
  hipMemsetAsync(ek_acc, 0, 3 * sizeof(float), stream);

  gather_kernel<<<(S*B*NS*D)/256, 256, 0, stream>>>(tok, embed, h_cur);

  for (int l = 0; l < LNUM; ++l) {
    float* P = prm + l*32;
    sink_kernel<<<1, 64, 0, stream>>>(H_logits + l*16, w_pre + l*4, w_post + l*4, P);
    mix_kernel<<<(S*B*D)/256, 256, 0, stream>>>(h_cur, P, h_mix, xbuf);
    plif_kernel<true,false><<<(B*D)/256, 256, 0, stream>>>(
        xbuf, nullptr, beta_in1 + l*D, vth_in1 + l*D, s1, D);
    { dim3 g(ND/128, (T*B)/128);
      sgemm_kernel<false,false><<<g,256,0,stream>>>(s1, W_in + (size_t)l*D*ND, nullptr, big1, T*B, ND, D); }
    plif_kernel<false,false><<<(B*ND)/256, 256, 0, stream>>>(
        big1, nullptr, beta_h + l*ND, vth_h + l*ND, big2, ND);
    { dim3 g(D/128, (T*B)/128);
      sgemm_kernel<false,false><<<g,256,0,stream>>>(big2, W_out + (size_t)l*ND*D, nullptr, y_blk, T*B, D, ND); }
    plif_kernel<true,true><<<(B*D)/256, 256, 0, stream>>>(
        xbuf, y_blk, beta_in2 + l*D, vth_in2 + l*D, s2, D);
    { dim3 g(DFF/128, (T*B)/128);
      sgemm_kernel<false,false><<<g,256,0,stream>>>(s2, W_gate + (size_t)l*D*DFF, nullptr, big1, T*B, DFF, D);
      sgemm_kernel<false,false><<<g,256,0,stream>>>(s2, W_up   + (size_t)l*D*DFF, nullptr, big2, T*B, DFF, D); }
    plif_gu_kernel<<<(B*DFF)/256, 256, 0, stream>>>(
        big1, big2, beta_gate + l*DFF, vth_gate + l*DFF, beta_up + l*DFF, vth_up + l*DFF);
    { dim3 g(D/128, (T*B)/128);
      sgemm_kernel<false,true><<<g,256,0,stream>>>(big1, W_down + (size_t)l*DFF*D, y_blk, y_blk, T*B, D, DFF); }
    halt_kernel<<<S*B, 256, 0, stream>>>(y_blk, h_mix, P, halt_w + l*D, halt_b + l, h_cur, ek_acc + l);
  }

  collnorm_kernel<<<S*B, 256, 0, stream>>>(h_cur, out_norm, xn);
  dplif_kernel<<<(B*D)/256, 256, 0, stream>>>(xn, beta_out, vth_out, dec);
  { dim3 g(D/128, (B*S)/128);
    sgemm_kernel<true,false><<<g,256,0,stream>>>(dec, decode_W, nullptr, hh, B*S, D, D); }
  li_kernel<<<B*S, 256, 0, stream>>>(hh, decode_b, norm_w);
  { dim3 g(VOCABSZ/128, (B*S)/128);
    sgemm_kernel<true,false><<<g,256,0,stream>>>(hh, embed, nullptr, out, B*S, VOCABSZ, D); }
  finalize_kernel<<<1, 1, 0, stream>>>(ek_acc, out + (out_size - 2));
}

// Round 2
// 2709.652 us; speedup vs baseline: 2.7480x; 2.7480x over previous
//
#include <hip/hip_runtime.h>
#include <hip/hip_bf16.h>

#define B 4
#define S 128
#define D 1024
#define NS 4
#define KF 8
#define LNUM 3
#define DFF 3072
#define ND 4096
#define T 1024          // S*KF
#define TB 4096         // T*B
#define VOCABSZ 6144
#define SINKIT 20

typedef unsigned short u16;
typedef __attribute__((ext_vector_type(8))) short short8;
typedef __attribute__((ext_vector_type(4))) float f32x4;

__device__ __forceinline__ void gload16(const void* g, void* l) {
  __builtin_amdgcn_global_load_lds(
      (const __attribute__((address_space(1))) void*)g,
      (__attribute__((address_space(3))) void*)l, 16, 0, 0);
}

// ---------------- sinkhorn + softmax(w_pre/w_post) ----------------
__global__ void sink_kernel(const float* __restrict__ Hl, const float* __restrict__ wpre,
                            const float* __restrict__ wpost, float* __restrict__ prm) {
  if (threadIdx.x != 0 || blockIdx.x != 0) return;
  float M[16];
  for (int i = 0; i < 16; ++i) M[i] = expf(Hl[i]);
  for (int it = 0; it < SINKIT; ++it) {
    for (int m = 0; m < 4; ++m) {
      float s = M[m*4+0] + M[m*4+1] + M[m*4+2] + M[m*4+3];
      for (int n = 0; n < 4; ++n) M[m*4+n] /= s;
    }
    for (int n = 0; n < 4; ++n) {
      float s = M[0*4+n] + M[1*4+n] + M[2*4+n] + M[3*4+n];
      for (int m = 0; m < 4; ++m) M[m*4+n] /= s;
    }
  }
  for (int i = 0; i < 16; ++i) prm[i] = M[i];
  float a[4], mx, sm;
  mx = fmaxf(fmaxf(wpre[0], wpre[1]), fmaxf(wpre[2], wpre[3]));
  sm = 0.f; for (int i = 0; i < 4; ++i) { a[i] = expf(wpre[i] - mx); sm += a[i]; }
  for (int i = 0; i < 4; ++i) prm[16+i] = a[i] / sm;
  mx = fmaxf(fmaxf(wpost[0], wpost[1]), fmaxf(wpost[2], wpost[3]));
  sm = 0.f; for (int i = 0; i < 4; ++i) { a[i] = expf(wpost[i] - mx); sm += a[i]; }
  for (int i = 0; i < 4; ++i) prm[20+i] = a[i] / sm;
}

// ---------------- embed gather ----------------
__global__ __launch_bounds__(256)
void gather_kernel(const int* __restrict__ tok, const float* __restrict__ embed,
                   float* __restrict__ h) {
  const int idx = blockIdx.x * 256 + threadIdx.x;
  const int d   = idx % D;
  const int sbn = idx / D;
  const int sb  = sbn / NS;
  const int b   = sb % B, s = sb / B;
  h[idx] = embed[(size_t)tok[b*S + s] * D + d];
}

// ---------------- stream mix ----------------
__global__ __launch_bounds__(256)
void mix_kernel(const float* __restrict__ h, const float* __restrict__ P,
                float* __restrict__ h_mix, float* __restrict__ x) {
  const int idx = blockIdx.x * 256 + threadIdx.x;
  const int d = idx % D, sb = idx / D;
  const float* hp = h + (size_t)sb * NS * D + d;
  const float h0 = hp[0], h1 = hp[D], h2 = hp[2*D], h3 = hp[3*D];
  float xv = 0.f;
  #pragma unroll
  for (int m = 0; m < 4; ++m) {
    float hm = P[m*4+0]*h0 + P[m*4+1]*h1 + P[m*4+2]*h2 + P[m*4+3]*h3;
    h_mix[(size_t)sb * NS * D + m*D + d] = hm;
    xv = fmaf(P[16+m], hm, xv);
  }
  x[idx] = xv;
}

// ---------------- PLIF scan -> binary bf16 spikes ----------------
template<bool R1, bool A2>
__global__ __launch_bounds__(256)
void plif_kernel(const float* __restrict__ z1, const float* __restrict__ z2,
                 const float* __restrict__ beta, const float* __restrict__ vth,
                 u16* __restrict__ outp, int C) {
  const int idx = blockIdx.x * 256 + threadIdx.x;
  const int c = idx % C;
  const int stride = B * C;
  const float be = beta[c], vt = vth[c], omb = 1.f - be;
  float v = 0.f;
  #pragma unroll 8
  for (int t = 0; t < T; ++t) {
    float xt = R1 ? z1[(size_t)(t >> 3) * stride + idx] : z1[(size_t)t * stride + idx];
    if (A2) xt += z2[(size_t)t * stride + idx];
    v = fmaf(be, v, omb * xt);
    const bool sp = (v >= vt);
    if (sp) v -= vt;
    outp[(size_t)t * stride + idx] = sp ? (u16)0x3F80 : (u16)0;
  }
}

// ---------------- fused gate+up PLIF -> binary AND spikes ----------------
__global__ __launch_bounds__(256)
void plif_gu_kernel(const float* __restrict__ zg, const float* __restrict__ zu,
                    const float* __restrict__ bg, const float* __restrict__ vg_,
                    const float* __restrict__ bu, const float* __restrict__ vu_,
                    u16* __restrict__ outp) {
  const int idx = blockIdx.x * 256 + threadIdx.x;
  const int c = idx % DFF;
  const int stride = B * DFF;
  const float beg = bg[c], vtg = vg_[c], beu = bu[c], vtu = vu_[c];
  const float og = 1.f - beg, ou = 1.f - beu;
  float vg = 0.f, vu = 0.f;
  #pragma unroll 8
  for (int t = 0; t < T; ++t) {
    const size_t off = (size_t)t * stride + idx;
    vg = fmaf(beg, vg, og * zg[off]);
    vu = fmaf(beu, vu, ou * zu[off]);
    const bool sg = (vg >= vtg), su = (vu >= vtu);
    if (sg) vg -= vtg;
    if (su) vu -= vtu;
    outp[off] = (sg && su) ? (u16)0x3F80 : (u16)0;
  }
}

// ---------------- weight prep: transpose + scale + bf16 hi/lo split ----------------
// In: W [Kd][Nd] fp32, scale s(k) = mult * sA[k] * sB[k]. Out: Wt_hi/lo [Nd][Kd] bf16.
__global__ __launch_bounds__(256)
void prep_t_kernel(const float* __restrict__ W, const float* __restrict__ sA,
                   const float* __restrict__ sB, float mult,
                   __hip_bfloat16* __restrict__ hi, __hip_bfloat16* __restrict__ lo,
                   int Kd, int Nd) {
  __shared__ float tile[64][65];
  const int tid = threadIdx.x;
  const int bn = blockIdx.x, bk = blockIdx.y;
  const int c = tid & 63, r0 = (tid >> 6) * 16;
  #pragma unroll
  for (int i = 0; i < 16; ++i) {
    const int r = r0 + i;
    const int kg = bk*64 + r;
    float s = mult;
    if (sA) s *= sA[kg];
    if (sB) s *= sB[kg];
    tile[r][c] = W[(size_t)kg * Nd + bn*64 + c] * s;
  }
  __syncthreads();
  #pragma unroll
  for (int i = 0; i < 16; ++i) {
    const int nl = r0 + i;
    const float v = tile[c][nl];
    const __hip_bfloat16 h = __float2bfloat16(v);
    const size_t off = (size_t)(bn*64 + nl) * Kd + bk*64 + c;
    hi[off] = h;
    lo[off] = __float2bfloat16(v - __bfloat162float(h));
  }
}

// ---------------- prep (no transpose): [Nd][Kd] -> scaled hi/lo split ----------------
__global__ __launch_bounds__(256)
void prep_nt_kernel(const float* __restrict__ W, const float* __restrict__ sK, float mult,
                    __hip_bfloat16* __restrict__ hi, __hip_bfloat16* __restrict__ lo,
                    int Kd) {
  const size_t idx = (size_t)blockIdx.x * 256 + threadIdx.x;
  const int k = (int)(idx % Kd);
  const float v = W[idx] * mult * (sK ? sK[k] : 1.f);
  const __hip_bfloat16 h = __float2bfloat16(v);
  hi[idx] = h;
  lo[idx] = __float2bfloat16(v - __bfloat162float(h));
}

// ---------------- bf16 MFMA GEMM: Cout = A @ (B0 [+B1])^T_layout [+ Cin] ----------------
// A: [M][K] bf16 row-major. B0/B1: [N][K] bf16 (B-transposed layout). 128x128 tile, BK=32.
template<int NB, bool ADDC>
__global__ __launch_bounds__(256)
void mgemm_kernel(const u16* __restrict__ A, const u16* __restrict__ B0,
                  const u16* __restrict__ B1, const float* __restrict__ Cin,
                  float* __restrict__ Cout, int M, int N, int K) {
  __shared__ __align__(16) char lds[24576];   // A 8K | B0 8K | B1 8K
  const int tid = threadIdx.x;
  const int lane = tid & 63, wv = tid >> 6;
  const int wm = wv >> 1, wn = wv & 1;
  const int bm = blockIdx.y, bn = blockIdx.x;
  const int lr = lane & 15, ks = lane >> 4;

  f32x4 acc[4][4];
  #pragma unroll
  for (int i = 0; i < 4; ++i)
    #pragma unroll
    for (int j = 0; j < 4; ++j) acc[i][j] = (f32x4){0.f, 0.f, 0.f, 0.f};

  const size_t am0 = (size_t)bm * 128, bn0 = (size_t)bn * 128;

  for (int k0 = 0; k0 < K; k0 += 32) {
    #pragma unroll
    for (int c = 0; c < 2; ++c) {
      const int bo = c*4096 + wv*1024 + lane*16;   // byte offset in 8KB tile
      const int row = bo >> 6, colb = bo & 63;
      const size_t ga = ((am0 + row) * (size_t)K + k0) * 2 + colb;
      const size_t gb = ((bn0 + row) * (size_t)K + k0) * 2 + colb;
      gload16((const char*)A + ga, lds + c*4096 + wv*1024);
      gload16((const char*)B0 + gb, lds + 8192 + c*4096 + wv*1024);
      if (NB == 2) gload16((const char*)B1 + gb, lds + 16384 + c*4096 + wv*1024);
    }
    __syncthreads();
    short8 af[4], b0f[4], b1f[4];
    #pragma unroll
    for (int f = 0; f < 4; ++f) {
      af[f]  = *(const short8*)(lds + (wm*64 + f*16 + lr)*64 + ks*16);
      b0f[f] = *(const short8*)(lds + 8192 + (wn*64 + f*16 + lr)*64 + ks*16);
      if (NB == 2)
        b1f[f] = *(const short8*)(lds + 16384 + (wn*64 + f*16 + lr)*64 + ks*16);
    }
    #pragma unroll
    for (int i = 0; i < 4; ++i)
      #pragma unroll
      for (int j = 0; j < 4; ++j) {
        acc[i][j] = __builtin_amdgcn_mfma_f32_16x16x32_bf16(af[i], b0f[j], acc[i][j], 0, 0, 0);
        if (NB == 2)
          acc[i][j] = __builtin_amdgcn_mfma_f32_16x16x32_bf16(af[i], b1f[j], acc[i][j], 0, 0, 0);
      }
    __syncthreads();
  }

  const int col0 = bn*128 + wn*64 + lr;
  #pragma unroll
  for (int i = 0; i < 4; ++i)
    #pragma unroll
    for (int j = 0; j < 4; ++j) {
      const size_t rbase = (size_t)(bm*128 + wm*64 + i*16 + ks*4);
      #pragma unroll
      for (int r = 0; r < 4; ++r) {
        const size_t idx = (rbase + r) * (size_t)N + col0 + j*16;
        float v = acc[i][j][r];
        if (ADDC) v += Cin[idx];
        Cout[idx] = v;
      }
    }
}

// ---------------- PonderNet halting + stream write-back ----------------
__global__ __launch_bounds__(256)
void halt_kernel(const float* __restrict__ y, const float* __restrict__ h_mix,
                 const float* __restrict__ P, const float* __restrict__ hw,
                 const float* __restrict__ hb, float* __restrict__ h_out,
                 float* __restrict__ ek_acc) {
  const int sb = blockIdx.x;
  const int b = sb % B, s = sb / B;
  const int tid = threadIdx.x;
  __shared__ float red[256];
  __shared__ float lam_s[KF];
  __shared__ float pk_s[KF];

  for (int k = 0; k < KF; ++k) {
    const float* yr = y + ((size_t)(s*KF + k) * B + b) * D;
    float p = 0.f;
    for (int d = tid; d < D; d += 256) p = fmaf(yr[d], hw[d], p);
    red[tid] = p; __syncthreads();
    for (int off = 128; off > 0; off >>= 1) {
      if (tid < off) red[tid] += red[tid + off];
      __syncthreads();
    }
    if (tid == 0) lam_s[k] = 1.f / (1.f + expf(-(red[0] + hb[0])));
    __syncthreads();
  }
  if (tid == 0) {
    float keep = 1.f, sum = 0.f, pk[KF];
    #pragma unroll
    for (int k = 0; k < KF; ++k) { pk[k] = lam_s[k] * keep; keep *= (1.f - lam_s[k]); sum += pk[k]; }
    pk[KF-1] += 1.f - sum;
    float ek = 0.f;
    #pragma unroll
    for (int k = 0; k < KF; ++k) { ek += pk[k] * (float)(k + 1); pk_s[k] = pk[k]; }
    atomicAdd(ek_acc, ek);
  }
  __syncthreads();
  for (int d = tid; d < D; d += 256) {
    float yt = 0.f;
    #pragma unroll
    for (int k = 0; k < KF; ++k)
      yt = fmaf(pk_s[k], y[((size_t)(s*KF + k) * B + b) * D + d], yt);
    #pragma unroll
    for (int n = 0; n < NS; ++n) {
      const size_t off = ((size_t)sb * NS + n) * D + d;
      h_out[off] = h_mix[off] + P[20+n] * yt;
    }
  }
}

// ---------------- decode: stream-collapse + rmsnorm ----------------
__global__ __launch_bounds__(256)
void collnorm_kernel(const float* __restrict__ h, const float* __restrict__ w,
                     float* __restrict__ xn) {
  const int sb = blockIdx.x, tid = threadIdx.x;
  __shared__ float red[256];
  float vals[4]; float ss = 0.f;
  #pragma unroll
  for (int i = 0; i < 4; ++i) {
    const int d = tid + i*256;
    const float* hp = h + (size_t)sb * NS * D + d;
    float m = 0.25f * (hp[0] + hp[D] + hp[2*D] + hp[3*D]);
    vals[i] = m; ss += m*m;
  }
  red[tid] = ss; __syncthreads();
  for (int off = 128; off > 0; off >>= 1) { if (tid < off) red[tid] += red[tid + off]; __syncthreads(); }
  const float inv = 1.f / sqrtf(red[0] * (1.f/(float)D) + 1e-6f);
  #pragma unroll
  for (int i = 0; i < 4; ++i) {
    const int d = tid + i*256;
    xn[(size_t)sb * D + d] = vals[i] * w[d] * inv;
  }
}

// ---------------- decode output PLIF -> spike counts (exact bf16 ints) ----------------
__global__ __launch_bounds__(256)
void dplif_kernel(const float* __restrict__ xn, const float* __restrict__ beta,
                  const float* __restrict__ vth, __hip_bfloat16* __restrict__ dec) {
  const int idx = blockIdx.x * 256 + threadIdx.x;
  const int b = idx / D, d = idx % D;
  const float be = beta[d], vt = vth[d], omb = 1.f - be;
  float v = 0.f;
  for (int s = 0; s < S; ++s) {
    const float xv = xn[((size_t)s * B + b) * D + d];
    float cnt = 0.f;
    #pragma unroll
    for (int k = 0; k < KF; ++k) {
      v = fmaf(be, v, omb * xv);
      if (v >= vt) { v -= vt; cnt += 1.f; }
    }
    dec[((size_t)b * S + s) * D + d] = __float2bfloat16(cnt);
  }
}

// ---------------- lateral inhibition (in-place, with bias add) ----------------
__global__ __launch_bounds__(256)
void li_kernel(float* __restrict__ hh, const float* __restrict__ bias,
               const float* __restrict__ w) {
  const int r = blockIdx.x, tid = threadIdx.x;
  __shared__ float red[256];
  float* row = hh + (size_t)r * D;
  float v[4]; float sm = 0.f;
  #pragma unroll
  for (int i = 0; i < 4; ++i) { const int d = tid + i*256; v[i] = row[d] + bias[d]; sm += v[i]; }
  red[tid] = sm; __syncthreads();
  for (int off = 128; off > 0; off >>= 1) { if (tid < off) red[tid] += red[tid + off]; __syncthreads(); }
  const float mean = red[0] * (1.f/(float)D);
  __syncthreads();
  float ss = 0.f;
  #pragma unroll
  for (int i = 0; i < 4; ++i) { v[i] -= mean; ss += v[i]*v[i]; }
  red[tid] = ss; __syncthreads();
  for (int off = 128; off > 0; off >>= 1) { if (tid < off) red[tid] += red[tid + off]; __syncthreads(); }
  const float inv = 1.f / sqrtf(red[0] * (1.f/(float)D) + 1e-6f);
  #pragma unroll
  for (int i = 0; i < 4; ++i) { const int d = tid + i*256; row[d] = w[d] * v[i] * inv; }
}

// ---------------- ponder / ekf tail ----------------
__global__ void finalize_kernel(const float* __restrict__ ek_acc, float* __restrict__ tail) {
  if (threadIdx.x != 0 || blockIdx.x != 0) return;
  float ponder = 0.f, ekf = 0.f;
  for (int l = 0; l < LNUM; ++l) {
    float ek = ek_acc[l] * (1.f/(float)(S*B));
    ponder += ek;
    ekf += fmaxf(0.f - ek, 0.f);
  }
  tail[0] = ponder * (1.f/(float)LNUM);
  tail[1] = ekf * (1.f/(float)LNUM);
}

extern "C" void kernel_launch(void* const* d_in, const int* in_sizes, int n_in,
                              void* d_out, int out_size, void* d_ws, size_t ws_size,
                              hipStream_t stream) {
  const int*   tok       = (const int*)  d_in[0];
  const float* embed     = (const float*)d_in[1];
  const float* norm_w    = (const float*)d_in[2];
  const float* decode_W  = (const float*)d_in[3];
  const float* decode_b  = (const float*)d_in[4];
  const float* out_norm  = (const float*)d_in[5];
  const float* beta_out  = (const float*)d_in[6];
  const float* vth_out   = (const float*)d_in[7];
  const float* H_logits  = (const float*)d_in[8];
  const float* w_pre     = (const float*)d_in[9];
  const float* w_post    = (const float*)d_in[10];
  const float* beta_in1  = (const float*)d_in[11];
  const float* vth_in1   = (const float*)d_in[12];
  const float* W_in      = (const float*)d_in[13];
  const float* beta_h    = (const float*)d_in[14];
  const float* vth_h     = (const float*)d_in[15];
  const float* W_out     = (const float*)d_in[16];
  const float* beta_in2  = (const float*)d_in[17];
  const float* vth_in2   = (const float*)d_in[18];
  const float* W_gate    = (const float*)d_in[19];
  const float* beta_gate = (const float*)d_in[20];
  const float* vth_gate  = (const float*)d_in[21];
  const float* W_up      = (const float*)d_in[22];
  const float* beta_up   = (const float*)d_in[23];
  const float* vth_up    = (const float*)d_in[24];
  const float* W_down    = (const float*)d_in[25];
  const float* halt_w    = (const float*)d_in[26];
  const float* halt_b    = (const float*)d_in[27];
  float* out = (float*)d_out;

  float* ws = (float*)d_ws;
  size_t o = 0;
  float* prm   = ws + o; o += 256;
  float* h_cur = ws + o; o += (size_t)S*B*NS*D;        // 2M
  float* h_mix = ws + o; o += (size_t)S*B*NS*D;        // 2M
  float* xbuf  = ws + o; o += (size_t)S*B*D;           // 0.5M
  float* y_blk = ws + o; o += (size_t)TB*D;            // 4M
  float* z1    = ws + o; o += (size_t)TB*ND;           // 16.8M (z_h / z_gate; decode: emb bf16)
  float* z2    = ws + o; o += (size_t)TB*DFF;          // 12.6M (z_up; decode: dwt/hh bf16)
  u16*   spb   = (u16*)(ws + o); o += (size_t)TB*ND/2; // 16.8M bf16 (sh / g*u spikes)
  u16*   s1b   = (u16*)(ws + o); o += (size_t)TB*D/2;
  u16*   s2b   = (u16*)(ws + o); o += (size_t)TB*D/2;
  float* xn    = ws + o; o += (size_t)S*B*D;
  __hip_bfloat16* decb = (__hip_bfloat16*)(ws + o); o += (size_t)B*S*D/2;
  float* hh    = ws + o; o += (size_t)B*S*D;
  __hip_bfloat16* wt_hi = (__hip_bfloat16*)(ws + o); o += (size_t)D*ND/2;   // 4M bf16
  __hip_bfloat16* wt_lo = (__hip_bfloat16*)(ws + o); o += (size_t)D*ND/2;
  if (ws_size < o * sizeof(float)) return;             // fail loudly (output stays poison/zero)

  float* ek_acc = prm + 96;
  hipMemsetAsync(ek_acc, 0, 3 * sizeof(float), stream);

  gather_kernel<<<(S*B*NS*D)/256, 256, 0, stream>>>(tok, embed, h_cur);

  for (int l = 0; l < LNUM; ++l) {
    float* P = prm + l*32;
    sink_kernel<<<1, 64, 0, stream>>>(H_logits + l*16, w_pre + l*4, w_post + l*4, P);
    mix_kernel<<<(S*B*D)/256, 256, 0, stream>>>(h_cur, P, h_mix, xbuf);
    plif_kernel<true,false><<<(B*D)/256, 256, 0, stream>>>(
        xbuf, nullptr, beta_in1 + l*D, vth_in1 + l*D, s1b, D);

    { dim3 gp(ND/64, D/64);
      prep_t_kernel<<<gp, 256, 0, stream>>>(W_in + (size_t)l*D*ND, vth_in1 + l*D, nullptr, 1.f,
                                            wt_hi, wt_lo, D, ND); }
    { dim3 g(ND/128, TB/128);
      mgemm_kernel<2,false><<<g, 256, 0, stream>>>(s1b, (const u16*)wt_hi, (const u16*)wt_lo,
                                                   nullptr, z1, TB, ND, D); }
    plif_kernel<false,false><<<(B*ND)/256, 256, 0, stream>>>(
        z1, nullptr, beta_h + l*ND, vth_h + l*ND, spb, ND);

    { dim3 gp(D/64, ND/64);
      prep_t_kernel<<<gp, 256, 0, stream>>>(W_out + (size_t)l*ND*D, vth_h + l*ND, nullptr, 1.f,
                                            wt_hi, wt_lo, ND, D); }
    { dim3 g(D/128, TB/128);
      mgemm_kernel<2,false><<<g, 256, 0, stream>>>(spb, (const u16*)wt_hi, (const u16*)wt_lo,
                                                   nullptr, y_blk, TB, D, ND); }
    plif_kernel<true,true><<<(B*D)/256, 256, 0, stream>>>(
        xbuf, y_blk, beta_in2 + l*D, vth_in2 + l*D, s2b, D);

    { dim3 gp(DFF/64, D/64);
      prep_t_kernel<<<gp, 256, 0, stream>>>(W_gate + (size_t)l*D*DFF, vth_in2 + l*D, nullptr, 1.f,
                                            wt_hi, wt_lo, D, DFF); }
    { dim3 g(DFF/128, TB/128);
      mgemm_kernel<2,false><<<g, 256, 0, stream>>>(s2b, (const u16*)wt_hi, (const u16*)wt_lo,
                                                   nullptr, z1, TB, DFF, D); }
    { dim3 gp(DFF/64, D/64);
      prep_t_kernel<<<gp, 256, 0, stream>>>(W_up + (size_t)l*D*DFF, vth_in2 + l*D, nullptr, 1.f,
                                            wt_hi, wt_lo, D, DFF); }
    { dim3 g(DFF/128, TB/128);
      mgemm_kernel<2,false><<<g, 256, 0, stream>>>(s2b, (const u16*)wt_hi, (const u16*)wt_lo,
                                                   nullptr, z2, TB, DFF, D); }
    plif_gu_kernel<<<(B*DFF)/256, 256, 0, stream>>>(
        z1, z2, beta_gate + l*DFF, vth_gate + l*DFF, beta_up + l*DFF, vth_up + l*DFF, spb);

    { dim3 gp(D/64, DFF/64);
      prep_t_kernel<<<gp, 256, 0, stream>>>(W_down + (size_t)l*DFF*D, vth_gate + l*DFF,
                                            vth_up + l*DFF, 1.f, wt_hi, wt_lo, DFF, D); }
    { dim3 g(D/128, TB/128);
      mgemm_kernel<2,true><<<g, 256, 0, stream>>>(spb, (const u16*)wt_hi, (const u16*)wt_lo,
                                                  y_blk, y_blk, TB, D, DFF); }
    halt_kernel<<<S*B, 256, 0, stream>>>(y_blk, h_mix, P, halt_w + l*D, halt_b + l, h_cur, ek_acc + l);
  }

  collnorm_kernel<<<S*B, 256, 0, stream>>>(h_cur, out_norm, xn);
  dplif_kernel<<<(B*D)/256, 256, 0, stream>>>(xn, beta_out, vth_out, decb);

  // decode GEMM: A = spike counts (exact), B^T = decode_W with vth_out/8 folded along K
  __hip_bfloat16* dwt_hi = (__hip_bfloat16*)z2;
  __hip_bfloat16* dwt_lo = (__hip_bfloat16*)(z2 + 524288);
  __hip_bfloat16* hh_hi  = (__hip_bfloat16*)(z2 + 1048576);
  __hip_bfloat16* hh_lo  = (__hip_bfloat16*)(z2 + 1310720);
  __hip_bfloat16* emb_hi = (__hip_bfloat16*)z1;
  __hip_bfloat16* emb_lo = (__hip_bfloat16*)(z1 + 3145728);

  prep_nt_kernel<<<(D*D)/256, 256, 0, stream>>>(decode_W, vth_out, 0.125f, dwt_hi, dwt_lo, D);
  { dim3 g(D/128, (B*S)/128);
    mgemm_kernel<2,false><<<g, 256, 0, stream>>>((const u16*)decb, (const u16*)dwt_hi,
                                                 (const u16*)dwt_lo, nullptr, hh, B*S, D, D); }
  li_kernel<<<B*S, 256, 0, stream>>>(hh, decode_b, norm_w);

  prep_nt_kernel<<<(B*S*D)/256, 256, 0, stream>>>(hh, nullptr, 1.f, hh_hi, hh_lo, D);
  prep_nt_kernel<<<(VOCABSZ*D)/256, 256, 0, stream>>>(embed, nullptr, 1.f, emb_hi, emb_lo, D);
  { dim3 g(VOCABSZ/128, (B*S)/128);
    mgemm_kernel<2,false><<<g, 256, 0, stream>>>((const u16*)hh_hi, (const u16*)emb_hi,
                                                 (const u16*)emb_lo, nullptr, out, B*S, VOCABSZ, D);
    mgemm_kernel<1,true><<<g, 256, 0, stream>>>((const u16*)hh_lo, (const u16*)emb_hi,
                                                nullptr, out, out, B*S, VOCABSZ, D); }
  finalize_kernel<<<1, 1, 0, stream>>>(ek_acc, out + (out_size - 2));
}

// Round 5
// 2570.550 us; speedup vs baseline: 2.8967x; 1.0541x over previous
//
#include <hip/hip_runtime.h>
#include <hip/hip_bf16.h>

#define B 4
#define S 128
#define D 1024
#define NS 4
#define KF 8
#define LNUM 3
#define DFF 3072
#define ND 4096
#define T 1024          // S*KF
#define TB 4096         // T*B
#define VOCABSZ 6144
#define SINKIT 20

typedef unsigned short u16;
typedef __attribute__((ext_vector_type(8))) short short8;
typedef __attribute__((ext_vector_type(4))) float f32x4;

__device__ __forceinline__ void gload16(const void* g, void* l) {
  __builtin_amdgcn_global_load_lds(
      (const __attribute__((address_space(1))) void*)g,
      (__attribute__((address_space(3))) void*)l, 16, 0, 0);
}

// ---------------- sinkhorn + softmax(w_pre/w_post) ----------------
__global__ void sink_kernel(const float* __restrict__ Hl, const float* __restrict__ wpre,
                            const float* __restrict__ wpost, float* __restrict__ prm) {
  if (threadIdx.x != 0 || blockIdx.x != 0) return;
  float M[16];
  for (int i = 0; i < 16; ++i) M[i] = expf(Hl[i]);
  for (int it = 0; it < SINKIT; ++it) {
    for (int m = 0; m < 4; ++m) {
      float s = M[m*4+0] + M[m*4+1] + M[m*4+2] + M[m*4+3];
      for (int n = 0; n < 4; ++n) M[m*4+n] /= s;
    }
    for (int n = 0; n < 4; ++n) {
      float s = M[0*4+n] + M[1*4+n] + M[2*4+n] + M[3*4+n];
      for (int m = 0; m < 4; ++m) M[m*4+n] /= s;
    }
  }
  for (int i = 0; i < 16; ++i) prm[i] = M[i];
  float a[4], mx, sm;
  mx = fmaxf(fmaxf(wpre[0], wpre[1]), fmaxf(wpre[2], wpre[3]));
  sm = 0.f; for (int i = 0; i < 4; ++i) { a[i] = expf(wpre[i] - mx); sm += a[i]; }
  for (int i = 0; i < 4; ++i) prm[16+i] = a[i] / sm;
  mx = fmaxf(fmaxf(wpost[0], wpost[1]), fmaxf(wpost[2], wpost[3]));
  sm = 0.f; for (int i = 0; i < 4; ++i) { a[i] = expf(wpost[i] - mx); sm += a[i]; }
  for (int i = 0; i < 4; ++i) prm[20+i] = a[i] / sm;
}

// ---------------- embed gather ----------------
__global__ __launch_bounds__(256)
void gather_kernel(const int* __restrict__ tok, const float* __restrict__ embed,
                   float* __restrict__ h) {
  const int idx = blockIdx.x * 256 + threadIdx.x;
  const int d   = idx % D;
  const int sbn = idx / D;
  const int sb  = sbn / NS;
  const int b   = sb % B, s = sb / B;
  h[idx] = embed[(size_t)tok[b*S + s] * D + d];
}

// ---------------- stream mix ----------------
__global__ __launch_bounds__(256)
void mix_kernel(const float* __restrict__ h, const float* __restrict__ P,
                float* __restrict__ h_mix, float* __restrict__ x) {
  const int idx = blockIdx.x * 256 + threadIdx.x;
  const int d = idx % D, sb = idx / D;
  const float* hp = h + (size_t)sb * NS * D + d;
  const float h0 = hp[0], h1 = hp[D], h2 = hp[2*D], h3 = hp[3*D];
  float xv = 0.f;
  #pragma unroll
  for (int m = 0; m < 4; ++m) {
    float hm = P[m*4+0]*h0 + P[m*4+1]*h1 + P[m*4+2]*h2 + P[m*4+3]*h3;
    h_mix[(size_t)sb * NS * D + m*D + d] = hm;
    xv = fmaf(P[16+m], hm, xv);
  }
  x[idx] = xv;
}

// ---------------- PLIF scan -> binary bf16 spikes ----------------
template<bool R1, bool A2>
__global__ __launch_bounds__(256)
void plif_kernel(const float* __restrict__ z1, const float* __restrict__ z2,
                 const float* __restrict__ beta, const float* __restrict__ vth,
                 u16* __restrict__ outp, int C) {
  const int idx = blockIdx.x * 256 + threadIdx.x;
  const int c = idx % C;
  const int stride = B * C;
  const float be = beta[c], vt = vth[c], omb = 1.f - be;
  float v = 0.f;
  #pragma unroll 16
  for (int t = 0; t < T; ++t) {
    float xt = R1 ? z1[(size_t)(t >> 3) * stride + idx] : z1[(size_t)t * stride + idx];
    if (A2) xt += z2[(size_t)t * stride + idx];
    v = fmaf(be, v, omb * xt);
    const bool sp = (v >= vt);
    if (sp) v -= vt;
    outp[(size_t)t * stride + idx] = sp ? (u16)0x3F80 : (u16)0;
  }
}

// ---------------- fused gate+up PLIF -> binary AND spikes ----------------
__global__ __launch_bounds__(256)
void plif_gu_kernel(const float* __restrict__ zg, const float* __restrict__ zu,
                    const float* __restrict__ bg, const float* __restrict__ vg_,
                    const float* __restrict__ bu, const float* __restrict__ vu_,
                    u16* __restrict__ outp) {
  const int idx = blockIdx.x * 256 + threadIdx.x;
  const int c = idx % DFF;
  const int stride = B * DFF;
  const float beg = bg[c], vtg = vg_[c], beu = bu[c], vtu = vu_[c];
  const float og = 1.f - beg, ou = 1.f - beu;
  float vg = 0.f, vu = 0.f;
  #pragma unroll 16
  for (int t = 0; t < T; ++t) {
    const size_t off = (size_t)t * stride + idx;
    vg = fmaf(beg, vg, og * zg[off]);
    vu = fmaf(beu, vu, ou * zu[off]);
    const bool sg = (vg >= vtg), su = (vu >= vtu);
    if (sg) vg -= vtg;
    if (su) vu -= vtu;
    outp[off] = (sg && su) ? (u16)0x3F80 : (u16)0;
  }
}

// ---------------- weight prep: transpose + scale + bf16 hi/lo split -> [N][2K] ----------------
__global__ __launch_bounds__(256)
void prep_t_kernel(const float* __restrict__ W, const float* __restrict__ sA,
                   const float* __restrict__ sB, float mult,
                   u16* __restrict__ wt, int Kd, int Nd) {
  __shared__ float tile[64][65];
  const int tid = threadIdx.x;
  const int bn = blockIdx.x, bk = blockIdx.y;
  const int c = tid & 63, r0 = (tid >> 6) * 16;
  #pragma unroll
  for (int i = 0; i < 16; ++i) {
    const int r = r0 + i;
    const int kg = bk*64 + r;
    float s = mult;
    if (sA) s *= sA[kg];
    if (sB) s *= sB[kg];
    tile[r][c] = W[(size_t)kg * Nd + bn*64 + c] * s;
  }
  __syncthreads();
  const int K2 = 2 * Kd;
  #pragma unroll
  for (int i = 0; i < 16; ++i) {
    const int nl = r0 + i;
    const float v = tile[c][nl];
    const __hip_bfloat16 h = __float2bfloat16(v);
    const size_t off = (size_t)(bn*64 + nl) * K2 + bk*64 + c;
    wt[off] = *(const u16*)&h;
    const __hip_bfloat16 lo = __float2bfloat16(v - __bfloat162float(h));
    wt[off + Kd] = *(const u16*)&lo;
  }
}

// ---------------- prep (no transpose): W [Nd][Kd] -> wt [Nd][2Kd] hi|lo ----------------
__global__ __launch_bounds__(256)
void prep_nt_kernel(const float* __restrict__ W, const float* __restrict__ sK, float mult,
                    u16* __restrict__ wt, int Kd) {
  const size_t idx = (size_t)blockIdx.x * 256 + threadIdx.x;
  const int k = (int)(idx % Kd);
  const size_t n = idx / Kd;
  const float v = W[idx] * mult * (sK ? sK[k] : 1.f);
  const __hip_bfloat16 h = __float2bfloat16(v);
  const size_t off = n * (2*Kd) + k;
  wt[off] = *(const u16*)&h;
  const __hip_bfloat16 lo = __float2bfloat16(v - __bfloat162float(h));
  wt[off + Kd] = *(const u16*)&lo;
}

// ---------------- bf16 MFMA GEMM, global_load_lds double-buffered 2-phase ----------------
// A: [M][Astride] bf16; k-offset wraps once: aoff = k0>=AW ? k0-AW : k0.
// Bm: [N][Bstride] bf16;                    boff = k0>=BW ? k0-BW : k0.  (K2 = loop extent)
// 128x128 tile, BK=32, 256 threads (4 waves), bijective XCD swizzle.
// STAGE(t+1) issued before compute(t); one barrier per tile (drains vmcnt after compute).
template<bool ADDC>
__global__ __launch_bounds__(256)
void mgemm2_kernel(const u16* __restrict__ A, const u16* __restrict__ Bm,
                   const float* __restrict__ Cin, float* __restrict__ Cout,
                   int M, int N, int Astride, int AW, int BW, int Bstride, int K2) {
  __shared__ __align__(16) char lds[32768];   // [buf0: A 8K | B 8K][buf1: A 8K | B 8K]
  const int tid = threadIdx.x;
  const int lane = tid & 63, wv = tid >> 6;
  const int wm = wv >> 1, wn = wv & 1;
  const int lr = lane & 15, ks = lane >> 4;

  // bijective XCD swizzle (all grids here are multiples of 8)
  const int gx = gridDim.x;
  const int nwg = gx * gridDim.y;
  int flat = blockIdx.y * gx + blockIdx.x;
  flat = (flat & 7) * (nwg >> 3) + (flat >> 3);
  const int bn = flat % gx, bm = flat / gx;

  f32x4 acc[4][4];
  #pragma unroll
  for (int i = 0; i < 4; ++i)
    #pragma unroll
    for (int j = 0; j < 4; ++j) acc[i][j] = (f32x4){0.f, 0.f, 0.f, 0.f};

  const size_t am0 = (size_t)bm * 128, bn0 = (size_t)bn * 128;

  // wave-uniform LDS dest (HW adds lane*16); per-lane global source (R2-proven pattern)
#define STAGE(bufbase, k0) do {                                                  \
    const int aoff_ = ((k0) >= AW) ? (k0) - AW : (k0);                           \
    const int boff_ = ((k0) >= BW) ? (k0) - BW : (k0);                           \
    _Pragma("unroll")                                                            \
    for (int c_ = 0; c_ < 2; ++c_) {                                             \
      const int bo_ = c_*4096 + wv*1024 + lane*16;                               \
      const int row_ = bo_ >> 6, colb_ = bo_ & 63;                               \
      gload16((const char*)A + ((am0 + row_) * (size_t)Astride + aoff_) * 2 + colb_, \
              lds + (bufbase) + c_*4096 + wv*1024);                              \
      gload16((const char*)Bm + ((bn0 + row_) * (size_t)Bstride + boff_) * 2 + colb_, \
              lds + (bufbase) + 8192 + c_*4096 + wv*1024);                       \
    }                                                                            \
  } while (0)

  const int nt = K2 >> 5;
  STAGE(0, 0);
  __syncthreads();
  int cur = 0;
  for (int t = 0; t < nt; ++t) {
    if (t + 1 < nt) STAGE((cur ^ 1) * 16384, (t + 1) << 5);  // in flight under compute
    const char* la = lds + cur * 16384;
    const char* lb = la + 8192;
    short8 af[4], bf[4];
    #pragma unroll
    for (int f = 0; f < 4; ++f) {
      af[f] = *(const short8*)(la + (wm*64 + f*16 + lr)*64 + ks*16);
      bf[f] = *(const short8*)(lb + (wn*64 + f*16 + lr)*64 + ks*16);
    }
    #pragma unroll
    for (int i = 0; i < 4; ++i)
      #pragma unroll
      for (int j = 0; j < 4; ++j)
        acc[i][j] = __builtin_amdgcn_mfma_f32_16x16x32_bf16(af[i], bf[j], acc[i][j], 0, 0, 0);
    __syncthreads();
    cur ^= 1;
  }
#undef STAGE

  const int col0 = bn*128 + wn*64 + lr;
  #pragma unroll
  for (int i = 0; i < 4; ++i)
    #pragma unroll
    for (int j = 0; j < 4; ++j) {
      const size_t rbase = (size_t)(bm*128 + wm*64 + i*16 + ks*4);
      #pragma unroll
      for (int r = 0; r < 4; ++r) {
        const size_t idx = (rbase + r) * (size_t)N + col0 + j*16;
        float v = acc[i][j][r];
        if (ADDC) v += Cin[idx];
        Cout[idx] = v;
      }
    }
}

// ---------------- PonderNet halting + stream write-back ----------------
__global__ __launch_bounds__(256)
void halt_kernel(const float* __restrict__ y, const float* __restrict__ h_mix,
                 const float* __restrict__ P, const float* __restrict__ hw,
                 const float* __restrict__ hb, float* __restrict__ h_out,
                 float* __restrict__ ek_acc) {
  const int sb = blockIdx.x;
  const int b = sb % B, s = sb / B;
  const int tid = threadIdx.x;
  __shared__ float red[256];
  __shared__ float lam_s[KF];
  __shared__ float pk_s[KF];

  for (int k = 0; k < KF; ++k) {
    const float* yr = y + ((size_t)(s*KF + k) * B + b) * D;
    float p = 0.f;
    for (int d = tid; d < D; d += 256) p = fmaf(yr[d], hw[d], p);
    red[tid] = p; __syncthreads();
    for (int off = 128; off > 0; off >>= 1) {
      if (tid < off) red[tid] += red[tid + off];
      __syncthreads();
    }
    if (tid == 0) lam_s[k] = 1.f / (1.f + expf(-(red[0] + hb[0])));
    __syncthreads();
  }
  if (tid == 0) {
    float keep = 1.f, sum = 0.f, pk[KF];
    #pragma unroll
    for (int k = 0; k < KF; ++k) { pk[k] = lam_s[k] * keep; keep *= (1.f - lam_s[k]); sum += pk[k]; }
    pk[KF-1] += 1.f - sum;
    float ek = 0.f;
    #pragma unroll
    for (int k = 0; k < KF; ++k) { ek += pk[k] * (float)(k + 1); pk_s[k] = pk[k]; }
    atomicAdd(ek_acc, ek);
  }
  __syncthreads();
  for (int d = tid; d < D; d += 256) {
    float yt = 0.f;
    #pragma unroll
    for (int k = 0; k < KF; ++k)
      yt = fmaf(pk_s[k], y[((size_t)(s*KF + k) * B + b) * D + d], yt);
    #pragma unroll
    for (int n = 0; n < NS; ++n) {
      const size_t off = ((size_t)sb * NS + n) * D + d;
      h_out[off] = h_mix[off] + P[20+n] * yt;
    }
  }
}

// ---------------- decode: stream-collapse + rmsnorm ----------------
__global__ __launch_bounds__(256)
void collnorm_kernel(const float* __restrict__ h, const float* __restrict__ w,
                     float* __restrict__ xn) {
  const int sb = blockIdx.x, tid = threadIdx.x;
  __shared__ float red[256];
  float vals[4]; float ss = 0.f;
  #pragma unroll
  for (int i = 0; i < 4; ++i) {
    const int d = tid + i*256;
    const float* hp = h + (size_t)sb * NS * D + d;
    float m = 0.25f * (hp[0] + hp[D] + hp[2*D] + hp[3*D]);
    vals[i] = m; ss += m*m;
  }
  red[tid] = ss; __syncthreads();
  for (int off = 128; off > 0; off >>= 1) { if (tid < off) red[tid] += red[tid + off]; __syncthreads(); }
  const float inv = 1.f / sqrtf(red[0] * (1.f/(float)D) + 1e-6f);
  #pragma unroll
  for (int i = 0; i < 4; ++i) {
    const int d = tid + i*256;
    xn[(size_t)sb * D + d] = vals[i] * w[d] * inv;
  }
}

// ---------------- decode output PLIF -> spike counts (exact bf16 ints) ----------------
__global__ __launch_bounds__(256)
void dplif_kernel(const float* __restrict__ xn, const float* __restrict__ beta,
                  const float* __restrict__ vth, u16* __restrict__ dec) {
  const int idx = blockIdx.x * 256 + threadIdx.x;
  const int b = idx / D, d = idx % D;
  const float be = beta[d], vt = vth[d], omb = 1.f - be;
  float v = 0.f;
  for (int s = 0; s < S; ++s) {
    const float xv = xn[((size_t)s * B + b) * D + d];
    float cnt = 0.f;
    #pragma unroll
    for (int k = 0; k < KF; ++k) {
      v = fmaf(be, v, omb * xv);
      if (v >= vt) { v -= vt; cnt += 1.f; }
    }
    const __hip_bfloat16 hb_ = __float2bfloat16(cnt);
    dec[((size_t)b * S + s) * D + d] = *(const u16*)&hb_;
  }
}

// ---------------- lateral inhibition (in-place, with bias add) ----------------
__global__ __launch_bounds__(256)
void li_kernel(float* __restrict__ hh, const float* __restrict__ bias,
               const float* __restrict__ w) {
  const int r = blockIdx.x, tid = threadIdx.x;
  __shared__ float red[256];
  float* row = hh + (size_t)r * D;
  float v[4]; float sm = 0.f;
  #pragma unroll
  for (int i = 0; i < 4; ++i) { const int d = tid + i*256; v[i] = row[d] + bias[d]; sm += v[i]; }
  red[tid] = sm; __syncthreads();
  for (int off = 128; off > 0; off >>= 1) { if (tid < off) red[tid] += red[tid + off]; __syncthreads(); }
  const float mean = red[0] * (1.f/(float)D);
  __syncthreads();
  float ss = 0.f;
  #pragma unroll
  for (int i = 0; i < 4; ++i) { v[i] -= mean; ss += v[i]*v[i]; }
  red[tid] = ss; __syncthreads();
  for (int off = 128; off > 0; off >>= 1) { if (tid < off) red[tid] += red[tid + off]; __syncthreads(); }
  const float inv = 1.f / sqrtf(red[0] * (1.f/(float)D) + 1e-6f);
  #pragma unroll
  for (int i = 0; i < 4; ++i) { const int d = tid + i*256; row[d] = w[d] * v[i] * inv; }
}

// ---------------- hi/lo split of a fp32 activation matrix [M][Kd] -> [M][2Kd] ----------------
__global__ __launch_bounds__(256)
void split_kernel(const float* __restrict__ X, u16* __restrict__ xs, int Kd) {
  const size_t idx = (size_t)blockIdx.x * 256 + threadIdx.x;
  const int k = (int)(idx % Kd);
  const size_t n = idx / Kd;
  const float v = X[idx];
  const __hip_bfloat16 h = __float2bfloat16(v);
  const size_t off = n * (2*Kd) + k;
  xs[off] = *(const u16*)&h;
  const __hip_bfloat16 lo = __float2bfloat16(v - __bfloat162float(h));
  xs[off + Kd] = *(const u16*)&lo;
}

// ---------------- ponder / ekf tail ----------------
__global__ void finalize_kernel(const float* __restrict__ ek_acc, float* __restrict__ tail) {
  if (threadIdx.x != 0 || blockIdx.x != 0) return;
  float ponder = 0.f, ekf = 0.f;
  for (int l = 0; l < LNUM; ++l) {
    float ek = ek_acc[l] * (1.f/(float)(S*B));
    ponder += ek;
    ekf += fmaxf(0.f - ek, 0.f);
  }
  tail[0] = ponder * (1.f/(float)LNUM);
  tail[1] = ekf * (1.f/(float)LNUM);
}

extern "C" void kernel_launch(void* const* d_in, const int* in_sizes, int n_in,
                              void* d_out, int out_size, void* d_ws, size_t ws_size,
                              hipStream_t stream) {
  const int*   tok       = (const int*)  d_in[0];
  const float* embed     = (const float*)d_in[1];
  const float* norm_w    = (const float*)d_in[2];
  const float* decode_W  = (const float*)d_in[3];
  const float* decode_b  = (const float*)d_in[4];
  const float* out_norm  = (const float*)d_in[5];
  const float* beta_out  = (const float*)d_in[6];
  const float* vth_out   = (const float*)d_in[7];
  const float* H_logits  = (const float*)d_in[8];
  const float* w_pre     = (const float*)d_in[9];
  const float* w_post    = (const float*)d_in[10];
  const float* beta_in1  = (const float*)d_in[11];
  const float* vth_in1   = (const float*)d_in[12];
  const float* W_in      = (const float*)d_in[13];
  const float* beta_h    = (const float*)d_in[14];
  const float* vth_h     = (const float*)d_in[15];
  const float* W_out     = (const float*)d_in[16];
  const float* beta_in2  = (const float*)d_in[17];
  const float* vth_in2   = (const float*)d_in[18];
  const float* W_gate    = (const float*)d_in[19];
  const float* beta_gate = (const float*)d_in[20];
  const float* vth_gate  = (const float*)d_in[21];
  const float* W_up      = (const float*)d_in[22];
  const float* beta_up   = (const float*)d_in[23];
  const float* vth_up    = (const float*)d_in[24];
  const float* W_down    = (const float*)d_in[25];
  const float* halt_w    = (const float*)d_in[26];
  const float* halt_b    = (const float*)d_in[27];
  float* out = (float*)d_out;

  float* ws = (float*)d_ws;
  size_t o = 0;
  float* prm   = ws + o; o += 256;
  float* h_cur = ws + o; o += (size_t)S*B*NS*D;        // 2.10M f
  float* h_mix = ws + o; o += (size_t)S*B*NS*D;        // 2.10M
  float* xbuf  = ws + o; o += (size_t)S*B*D;           // 0.52M
  float* y_blk = ws + o; o += (size_t)TB*D;            // 4.19M
  float* z1    = ws + o; o += (size_t)TB*ND;           // 16.78M (z_h / z_up; decode: emb split)
  float* z2    = ws + o; o += (size_t)TB*DFF;          // 12.58M (z_gate; decode: hh split)
  u16*   spb   = (u16*)(ws + o); o += (size_t)TB*ND/2; // sh spikes / g*u spikes
  u16*   s1b   = (u16*)(ws + o); o += (size_t)TB*D/2;
  u16*   s2b   = (u16*)(ws + o); o += (size_t)TB*D/2;
  float* xn    = ws + o; o += (size_t)S*B*D;
  u16*   decb  = (u16*)(ws + o); o += (size_t)B*S*D/2;
  float* hh    = ws + o; o += (size_t)B*S*D;
  u16*   wt    = (u16*)(ws + o); o += (size_t)D*ND;    // holds [N][2K] splits up to 2*ND*D u16
  if (ws_size < o * sizeof(float)) return;             // fail loudly (output stays poison/zero)

  float* ek_acc = prm + 96;
  hipMemsetAsync(ek_acc, 0, 3 * sizeof(float), stream);

  gather_kernel<<<(S*B*NS*D)/256, 256, 0, stream>>>(tok, embed, h_cur);

  for (int l = 0; l < LNUM; ++l) {
    float* P = prm + l*32;
    sink_kernel<<<1, 64, 0, stream>>>(H_logits + l*16, w_pre + l*4, w_post + l*4, P);
    mix_kernel<<<(S*B*D)/256, 256, 0, stream>>>(h_cur, P, h_mix, xbuf);
    plif_kernel<true,false><<<(B*D)/256, 256, 0, stream>>>(
        xbuf, nullptr, beta_in1 + l*D, vth_in1 + l*D, s1b, D);

    // z_h = s1 @ W_in (vth_in1 folded): A [TB][1024], B [4096][2048], K2=2048
    { dim3 gp(ND/64, D/64);
      prep_t_kernel<<<gp, 256, 0, stream>>>(W_in + (size_t)l*D*ND, vth_in1 + l*D, nullptr, 1.f,
                                            wt, D, ND); }
    { dim3 g(ND/128, TB/128);
      mgemm2_kernel<false><<<g, 256, 0, stream>>>(s1b, wt, nullptr, z1, TB, ND,
                                                  D, D, 2*D, 2*D, 2*D); }
    plif_kernel<false,false><<<(B*ND)/256, 256, 0, stream>>>(
        z1, nullptr, beta_h + l*ND, vth_h + l*ND, spb, ND);

    // y_blk = sh @ W_out (vth_h folded): A [TB][4096], B [1024][8192], K2=8192
    { dim3 gp(D/64, ND/64);
      prep_t_kernel<<<gp, 256, 0, stream>>>(W_out + (size_t)l*ND*D, vth_h + l*ND, nullptr, 1.f,
                                            wt, ND, D); }
    { dim3 g(D/128, TB/128);
      mgemm2_kernel<false><<<g, 256, 0, stream>>>(spb, wt, nullptr, y_blk, TB, D,
                                                  ND, ND, 2*ND, 2*ND, 2*ND); }
    plif_kernel<true,true><<<(B*D)/256, 256, 0, stream>>>(
        xbuf, y_blk, beta_in2 + l*D, vth_in2 + l*D, s2b, D);

    // z_gate / z_up: A [TB][1024], B [3072][2048]
    { dim3 gp(DFF/64, D/64);
      prep_t_kernel<<<gp, 256, 0, stream>>>(W_gate + (size_t)l*D*DFF, vth_in2 + l*D, nullptr, 1.f,
                                            wt, D, DFF); }
    { dim3 g(DFF/128, TB/128);
      mgemm2_kernel<false><<<g, 256, 0, stream>>>(s2b, wt, nullptr, z2, TB, DFF,
                                                  D, D, 2*D, 2*D, 2*D); }
    { dim3 gp(DFF/64, D/64);
      prep_t_kernel<<<gp, 256, 0, stream>>>(W_up + (size_t)l*D*DFF, vth_in2 + l*D, nullptr, 1.f,
                                            wt, D, DFF); }
    { dim3 g(DFF/128, TB/128);
      mgemm2_kernel<false><<<g, 256, 0, stream>>>(s2b, wt, nullptr, z1, TB, DFF,
                                                  D, D, 2*D, 2*D, 2*D); }
    plif_gu_kernel<<<(B*DFF)/256, 256, 0, stream>>>(
        z2, z1, beta_gate + l*DFF, vth_gate + l*DFF, beta_up + l*DFF, vth_up + l*DFF, spb);

    // y += (g*u) @ W_down (vth_g*vth_u folded): A [TB][3072], B [1024][6144], K2=6144
    { dim3 gp(D/64, DFF/64);
      prep_t_kernel<<<gp, 256, 0, stream>>>(W_down + (size_t)l*DFF*D, vth_gate + l*DFF,
                                            vth_up + l*DFF, 1.f, wt, DFF, D); }
    { dim3 g(D/128, TB/128);
      mgemm2_kernel<true><<<g, 256, 0, stream>>>(spb, wt, y_blk, y_blk, TB, D,
                                                 DFF, DFF, 2*DFF, 2*DFF, 2*DFF); }
    halt_kernel<<<S*B, 256, 0, stream>>>(y_blk, h_mix, P, halt_w + l*D, halt_b + l, h_cur, ek_acc + l);
  }

  collnorm_kernel<<<S*B, 256, 0, stream>>>(h_cur, out_norm, xn);
  dplif_kernel<<<(B*D)/256, 256, 0, stream>>>(xn, beta_out, vth_out, decb);

  // hh = dec @ (decode_W * vth_out/8)^T: A=decb [512][1024] read twice, B [1024][2048]
  prep_nt_kernel<<<(D*D)/256, 256, 0, stream>>>(decode_W, vth_out, 0.125f, wt, D);
  { dim3 g(D/128, (B*S)/128);
    mgemm2_kernel<false><<<g, 256, 0, stream>>>(decb, wt, nullptr, hh, B*S, D,
                                                D, D, 2*D, 2*D, 2*D); }
  li_kernel<<<B*S, 256, 0, stream>>>(hh, decode_b, norm_w);

  // logits = hh @ embed^T, 3-term split: K2=3D loop over B [6144][2048] (Bstride=2D!)
  // k0 in [0,D): hh_hi . emb_hi ; [D,2D): hh_hi . emb_lo ; [2D,3D): hh_lo . emb_hi
  u16* hh_c  = (u16*)z2;
  u16* emb_c = (u16*)z1;
  split_kernel<<<(B*S*D)/256, 256, 0, stream>>>(hh, hh_c, D);
  prep_nt_kernel<<<(VOCABSZ*D)/256, 256, 0, stream>>>(embed, nullptr, 1.f, emb_c, D);
  { dim3 g(VOCABSZ/128, (B*S)/128);
    mgemm2_kernel<false><<<g, 256, 0, stream>>>(hh_c, emb_c, nullptr, out, B*S, VOCABSZ,
                                                2*D, D, 2*D, 2*D, 3*D); }
  finalize_kernel<<<1, 1, 0, stream>>>(ek_acc, out + (out_size - 2));
}

// Round 6
// 2544.805 us; speedup vs baseline: 2.9260x; 1.0101x over previous
//
#include <hip/hip_runtime.h>
#include <hip/hip_bf16.h>

#define B 4
#define S 128
#define D 1024
#define NS 4
#define KF 8
#define LNUM 3
#define DFF 3072
#define ND 4096
#define T 1024          // S*KF
#define TB 4096         // T*B
#define VOCABSZ 6144
#define SINKIT 20

typedef unsigned short u16;
typedef __attribute__((ext_vector_type(8))) short short8;
typedef __attribute__((ext_vector_type(4))) float f32x4;

__device__ __forceinline__ void gload16(const void* g, void* l) {
  __builtin_amdgcn_global_load_lds(
      (const __attribute__((address_space(1))) void*)g,
      (__attribute__((address_space(3))) void*)l, 16, 0, 0);
}

// ---------------- sinkhorn + softmax(w_pre/w_post) ----------------
__global__ void sink_kernel(const float* __restrict__ Hl, const float* __restrict__ wpre,
                            const float* __restrict__ wpost, float* __restrict__ prm) {
  if (threadIdx.x != 0 || blockIdx.x != 0) return;
  float M[16];
  for (int i = 0; i < 16; ++i) M[i] = expf(Hl[i]);
  for (int it = 0; it < SINKIT; ++it) {
    for (int m = 0; m < 4; ++m) {
      float s = M[m*4+0] + M[m*4+1] + M[m*4+2] + M[m*4+3];
      for (int n = 0; n < 4; ++n) M[m*4+n] /= s;
    }
    for (int n = 0; n < 4; ++n) {
      float s = M[0*4+n] + M[1*4+n] + M[2*4+n] + M[3*4+n];
      for (int m = 0; m < 4; ++m) M[m*4+n] /= s;
    }
  }
  for (int i = 0; i < 16; ++i) prm[i] = M[i];
  float a[4], mx, sm;
  mx = fmaxf(fmaxf(wpre[0], wpre[1]), fmaxf(wpre[2], wpre[3]));
  sm = 0.f; for (int i = 0; i < 4; ++i) { a[i] = expf(wpre[i] - mx); sm += a[i]; }
  for (int i = 0; i < 4; ++i) prm[16+i] = a[i] / sm;
  mx = fmaxf(fmaxf(wpost[0], wpost[1]), fmaxf(wpost[2], wpost[3]));
  sm = 0.f; for (int i = 0; i < 4; ++i) { a[i] = expf(wpost[i] - mx); sm += a[i]; }
  for (int i = 0; i < 4; ++i) prm[20+i] = a[i] / sm;
}

// ---------------- embed gather ----------------
__global__ __launch_bounds__(256)
void gather_kernel(const int* __restrict__ tok, const float* __restrict__ embed,
                   float* __restrict__ h) {
  const int idx = blockIdx.x * 256 + threadIdx.x;
  const int d   = idx % D;
  const int sbn = idx / D;
  const int sb  = sbn / NS;
  const int b   = sb % B, s = sb / B;
  h[idx] = embed[(size_t)tok[b*S + s] * D + d];
}

// ---------------- stream mix ----------------
__global__ __launch_bounds__(256)
void mix_kernel(const float* __restrict__ h, const float* __restrict__ P,
                float* __restrict__ h_mix, float* __restrict__ x) {
  const int idx = blockIdx.x * 256 + threadIdx.x;
  const int d = idx % D, sb = idx / D;
  const float* hp = h + (size_t)sb * NS * D + d;
  const float h0 = hp[0], h1 = hp[D], h2 = hp[2*D], h3 = hp[3*D];
  float xv = 0.f;
  #pragma unroll
  for (int m = 0; m < 4; ++m) {
    float hm = P[m*4+0]*h0 + P[m*4+1]*h1 + P[m*4+2]*h2 + P[m*4+3]*h3;
    h_mix[(size_t)sb * NS * D + m*D + d] = hm;
    xv = fmaf(P[16+m], hm, xv);
  }
  x[idx] = xv;
}

// ---------------- PLIF scan -> binary bf16 spikes ----------------
template<bool R1, bool A2>
__global__ __launch_bounds__(256)
void plif_kernel(const float* __restrict__ z1, const float* __restrict__ z2,
                 const float* __restrict__ beta, const float* __restrict__ vth,
                 u16* __restrict__ outp, int C) {
  const int idx = blockIdx.x * 256 + threadIdx.x;
  const int c = idx % C;
  const int stride = B * C;
  const float be = beta[c], vt = vth[c], omb = 1.f - be;
  float v = 0.f;
  #pragma unroll 16
  for (int t = 0; t < T; ++t) {
    float xt = R1 ? z1[(size_t)(t >> 3) * stride + idx] : z1[(size_t)t * stride + idx];
    if (A2) xt += z2[(size_t)t * stride + idx];
    v = fmaf(be, v, omb * xt);
    const bool sp = (v >= vt);
    if (sp) v -= vt;
    outp[(size_t)t * stride + idx] = sp ? (u16)0x3F80 : (u16)0;
  }
}

// ---------------- fused gate+up PLIF from fused z12 [t][b][6144] ----------------
__global__ __launch_bounds__(256)
void plif_gu_kernel(const float* __restrict__ z12,
                    const float* __restrict__ bg, const float* __restrict__ vg_,
                    const float* __restrict__ bu, const float* __restrict__ vu_,
                    u16* __restrict__ outp) {
  const int idx = blockIdx.x * 256 + threadIdx.x;   // over B*DFF
  const int c = idx % DFF, b = idx / DFF;
  const float beg = bg[c], vtg = vg_[c], beu = bu[c], vtu = vu_[c];
  const float og = 1.f - beg, ou = 1.f - beu;
  float vg = 0.f, vu = 0.f;
  #pragma unroll 16
  for (int t = 0; t < T; ++t) {
    const size_t off = ((size_t)t * B + b) * (2*DFF) + c;
    vg = fmaf(beg, vg, og * z12[off]);
    vu = fmaf(beu, vu, ou * z12[off + DFF]);
    const bool sg = (vg >= vtg), su = (vu >= vtu);
    if (sg) vg -= vtg;
    if (su) vu -= vtu;
    outp[(size_t)t * (B*DFF) + idx] = (sg && su) ? (u16)0x3F80 : (u16)0;
  }
}

// ---------------- weight prep: transpose + scale + bf16 hi/lo split -> [N][2K] ----------------
__global__ __launch_bounds__(256)
void prep_t_kernel(const float* __restrict__ W, const float* __restrict__ sA,
                   const float* __restrict__ sB, float mult,
                   u16* __restrict__ wt, int Kd, int Nd) {
  __shared__ float tile[64][65];
  const int tid = threadIdx.x;
  const int bn = blockIdx.x, bk = blockIdx.y;
  const int c = tid & 63, r0 = (tid >> 6) * 16;
  #pragma unroll
  for (int i = 0; i < 16; ++i) {
    const int r = r0 + i;
    const int kg = bk*64 + r;
    float s = mult;
    if (sA) s *= sA[kg];
    if (sB) s *= sB[kg];
    tile[r][c] = W[(size_t)kg * Nd + bn*64 + c] * s;
  }
  __syncthreads();
  const int K2 = 2 * Kd;
  #pragma unroll
  for (int i = 0; i < 16; ++i) {
    const int nl = r0 + i;
    const float v = tile[c][nl];
    const __hip_bfloat16 h = __float2bfloat16(v);
    const size_t off = (size_t)(bn*64 + nl) * K2 + bk*64 + c;
    wt[off] = *(const u16*)&h;
    const __hip_bfloat16 lo = __float2bfloat16(v - __bfloat162float(h));
    wt[off + Kd] = *(const u16*)&lo;
  }
}

// ---------------- prep (no transpose): W [Nd][Kd] -> wt [Nd][2Kd] hi|lo ----------------
__global__ __launch_bounds__(256)
void prep_nt_kernel(const float* __restrict__ W, const float* __restrict__ sK, float mult,
                    u16* __restrict__ wt, int Kd) {
  const size_t idx = (size_t)blockIdx.x * 256 + threadIdx.x;
  const int k = (int)(idx % Kd);
  const size_t n = idx / Kd;
  const float v = W[idx] * mult * (sK ? sK[k] : 1.f);
  const __hip_bfloat16 h = __float2bfloat16(v);
  const size_t off = n * (2*Kd) + k;
  wt[off] = *(const u16*)&h;
  const __hip_bfloat16 lo = __float2bfloat16(v - __bfloat162float(h));
  wt[off + Kd] = *(const u16*)&lo;
}

// ---------------- 128x128 bf16 MFMA GEMM (unchanged, proven) ----------------
template<bool ADDC>
__global__ __launch_bounds__(256)
void mgemm2_kernel(const u16* __restrict__ A, const u16* __restrict__ Bm,
                   const float* __restrict__ Cin, float* __restrict__ Cout,
                   int M, int N, int Astride, int AW, int BW, int Bstride, int K2) {
  __shared__ __align__(16) char lds[32768];
  const int tid = threadIdx.x;
  const int lane = tid & 63, wv = tid >> 6;
  const int wm = wv >> 1, wn = wv & 1;
  const int lr = lane & 15, ks = lane >> 4;

  const int gx = gridDim.x;
  const int nwg = gx * gridDim.y;
  int flat = blockIdx.y * gx + blockIdx.x;
  flat = (flat & 7) * (nwg >> 3) + (flat >> 3);
  const int bn = flat % gx, bm = flat / gx;

  f32x4 acc[4][4];
  #pragma unroll
  for (int i = 0; i < 4; ++i)
    #pragma unroll
    for (int j = 0; j < 4; ++j) acc[i][j] = (f32x4){0.f, 0.f, 0.f, 0.f};

  const size_t am0 = (size_t)bm * 128, bn0 = (size_t)bn * 128;

#define STAGE(bufbase, k0) do {                                                  \
    const int aoff_ = ((k0) >= AW) ? (k0) - AW : (k0);                           \
    const int boff_ = ((k0) >= BW) ? (k0) - BW : (k0);                           \
    _Pragma("unroll")                                                            \
    for (int c_ = 0; c_ < 2; ++c_) {                                             \
      const int bo_ = c_*4096 + wv*1024 + lane*16;                               \
      const int row_ = bo_ >> 6, colb_ = bo_ & 63;                               \
      gload16((const char*)A + ((am0 + row_) * (size_t)Astride + aoff_) * 2 + colb_, \
              lds + (bufbase) + c_*4096 + wv*1024);                              \
      gload16((const char*)Bm + ((bn0 + row_) * (size_t)Bstride + boff_) * 2 + colb_, \
              lds + (bufbase) + 8192 + c_*4096 + wv*1024);                       \
    }                                                                            \
  } while (0)

  const int nt = K2 >> 5;
  STAGE(0, 0);
  __syncthreads();
  int cur = 0;
  for (int t = 0; t < nt; ++t) {
    if (t + 1 < nt) STAGE((cur ^ 1) * 16384, (t + 1) << 5);
    const char* la = lds + cur * 16384;
    const char* lb = la + 8192;
    short8 af[4], bf[4];
    #pragma unroll
    for (int f = 0; f < 4; ++f) {
      af[f] = *(const short8*)(la + (wm*64 + f*16 + lr)*64 + ks*16);
      bf[f] = *(const short8*)(lb + (wn*64 + f*16 + lr)*64 + ks*16);
    }
    #pragma unroll
    for (int i = 0; i < 4; ++i)
      #pragma unroll
      for (int j = 0; j < 4; ++j)
        acc[i][j] = __builtin_amdgcn_mfma_f32_16x16x32_bf16(af[i], bf[j], acc[i][j], 0, 0, 0);
    __syncthreads();
    cur ^= 1;
  }
#undef STAGE

  const int col0 = bn*128 + wn*64 + lr;
  #pragma unroll
  for (int i = 0; i < 4; ++i)
    #pragma unroll
    for (int j = 0; j < 4; ++j) {
      const size_t rbase = (size_t)(bm*128 + wm*64 + i*16 + ks*4);
      #pragma unroll
      for (int r = 0; r < 4; ++r) {
        const size_t idx = (rbase + r) * (size_t)N + col0 + j*16;
        float v = acc[i][j][r];
        if (ADDC) v += Cin[idx];
        Cout[idx] = v;
      }
    }
}

// ---------------- 256x256 bf16 MFMA GEMM: counted-vmcnt 2-barrier, XOR-swizzled LDS ----
// A: [M][Astride] bf16, k wraps at AW. Bm: [N][K2] bf16 (stride==K2). C: [M][N] f32.
// 512 thr / 8 waves (2Mx4N), BK=32, 64KB LDS dbuf. Source pre-swizzle + swizzled ds_read
// (rule #21: linear gload_lds dest + inverse-swizzled global src + same XOR on read).
__global__ __launch_bounds__(512)
void mgemm3_kernel(const u16* __restrict__ A, const u16* __restrict__ Bm,
                   float* __restrict__ Cout, int M, int N, int Astride, int AW, int K2) {
  __shared__ __align__(16) char lds[65536];   // [buf: A 16K | B 16K] x2
  const int tid = threadIdx.x;
  const int lane = tid & 63, wv = tid >> 6;
  const int wm = wv >> 2, wn = wv & 3;
  const int lr = lane & 15, ks = lane >> 4;
  const int gsw = (lane & 3) ^ ((lane >> 2) & 3);  // stage-side source slot swizzle
  const int rsw = lr & 3;                          // read-side row&3

  const int gx = gridDim.x;
  const int nwg = gx * gridDim.y;
  int flat = blockIdx.y * gx + blockIdx.x;
  flat = (flat & 7) * (nwg >> 3) + (flat >> 3);
  const int bn = flat % gx, bm = flat / gx;

  f32x4 acc[8][4];
  #pragma unroll
  for (int i = 0; i < 8; ++i)
    #pragma unroll
    for (int j = 0; j < 4; ++j) acc[i][j] = (f32x4){0.f, 0.f, 0.f, 0.f};

  const size_t am0 = (size_t)bm * 256, bn0 = (size_t)bn * 256;

#define STG(base, k0) do {                                                        \
    const int aoff_ = ((k0) >= AW) ? (k0) - AW : (k0);                            \
    _Pragma("unroll")                                                             \
    for (int c_ = 0; c_ < 2; ++c_) {                                              \
      const int fl_ = c_*8192 + wv*1024 + lane*16;                                \
      const int row_ = fl_ >> 6;                                                  \
      gload16((const char*)A + ((am0 + row_) * (size_t)Astride + aoff_ + gsw*8) * 2, \
              lds + (base) + c_*8192 + wv*1024);                                  \
      gload16((const char*)Bm + ((bn0 + row_) * (size_t)K2 + (k0) + gsw*8) * 2,   \
              lds + (base) + 16384 + c_*8192 + wv*1024);                          \
    }                                                                             \
  } while (0)

  const int nt = K2 >> 5;
  STG(0, 0);
  for (int t = 0; t < nt; ++t) {
    // barrier A: everyone finished computing from buf[(t+1)&1] (iter t-1) before overwrite
    asm volatile("s_barrier" ::: "memory");
    if (t + 1 < nt) {
      STG(((t + 1) & 1) * 32768, (t + 1) << 5);
      // wait own stage(t) (4 newest = stage(t+1) stay in flight), then join
      asm volatile("s_waitcnt vmcnt(4)\n\ts_barrier" ::: "memory");
    } else {
      asm volatile("s_waitcnt vmcnt(0)\n\ts_barrier" ::: "memory");
    }
    const char* la = lds + (t & 1) * 32768;
    const char* lb = la + 16384;
    short8 af[8], bf[4];
    #pragma unroll
    for (int i = 0; i < 8; ++i)
      af[i] = *(const short8*)(la + (wm*128 + i*16 + lr)*64 + ((ks ^ rsw) * 16));
    #pragma unroll
    for (int j = 0; j < 4; ++j)
      bf[j] = *(const short8*)(lb + (wn*64 + j*16 + lr)*64 + ((ks ^ rsw) * 16));
    #pragma unroll
    for (int i = 0; i < 8; ++i)
      #pragma unroll
      for (int j = 0; j < 4; ++j)
        acc[i][j] = __builtin_amdgcn_mfma_f32_16x16x32_bf16(af[i], bf[j], acc[i][j], 0, 0, 0);
  }
#undef STG

  const int col0 = bn*256 + wn*64 + lr;
  #pragma unroll
  for (int i = 0; i < 8; ++i)
    #pragma unroll
    for (int j = 0; j < 4; ++j) {
      const size_t rbase = (size_t)(bm*256 + wm*128 + i*16 + ks*4);
      #pragma unroll
      for (int r = 0; r < 4; ++r)
        Cout[(rbase + r) * (size_t)N + col0 + j*16] = acc[i][j][r];
    }
}

// ---------------- PonderNet halting + stream write-back ----------------
__global__ __launch_bounds__(256)
void halt_kernel(const float* __restrict__ y, const float* __restrict__ h_mix,
                 const float* __restrict__ P, const float* __restrict__ hw,
                 const float* __restrict__ hb, float* __restrict__ h_out,
                 float* __restrict__ ek_acc) {
  const int sb = blockIdx.x;
  const int b = sb % B, s = sb / B;
  const int tid = threadIdx.x;
  __shared__ float red[256];
  __shared__ float lam_s[KF];
  __shared__ float pk_s[KF];

  for (int k = 0; k < KF; ++k) {
    const float* yr = y + ((size_t)(s*KF + k) * B + b) * D;
    float p = 0.f;
    for (int d = tid; d < D; d += 256) p = fmaf(yr[d], hw[d], p);
    red[tid] = p; __syncthreads();
    for (int off = 128; off > 0; off >>= 1) {
      if (tid < off) red[tid] += red[tid + off];
      __syncthreads();
    }
    if (tid == 0) lam_s[k] = 1.f / (1.f + expf(-(red[0] + hb[0])));
    __syncthreads();
  }
  if (tid == 0) {
    float keep = 1.f, sum = 0.f, pk[KF];
    #pragma unroll
    for (int k = 0; k < KF; ++k) { pk[k] = lam_s[k] * keep; keep *= (1.f - lam_s[k]); sum += pk[k]; }
    pk[KF-1] += 1.f - sum;
    float ek = 0.f;
    #pragma unroll
    for (int k = 0; k < KF; ++k) { ek += pk[k] * (float)(k + 1); pk_s[k] = pk[k]; }
    atomicAdd(ek_acc, ek);
  }
  __syncthreads();
  for (int d = tid; d < D; d += 256) {
    float yt = 0.f;
    #pragma unroll
    for (int k = 0; k < KF; ++k)
      yt = fmaf(pk_s[k], y[((size_t)(s*KF + k) * B + b) * D + d], yt);
    #pragma unroll
    for (int n = 0; n < NS; ++n) {
      const size_t off = ((size_t)sb * NS + n) * D + d;
      h_out[off] = h_mix[off] + P[20+n] * yt;
    }
  }
}

// ---------------- decode: stream-collapse + rmsnorm ----------------
__global__ __launch_bounds__(256)
void collnorm_kernel(const float* __restrict__ h, const float* __restrict__ w,
                     float* __restrict__ xn) {
  const int sb = blockIdx.x, tid = threadIdx.x;
  __shared__ float red[256];
  float vals[4]; float ss = 0.f;
  #pragma unroll
  for (int i = 0; i < 4; ++i) {
    const int d = tid + i*256;
    const float* hp = h + (size_t)sb * NS * D + d;
    float m = 0.25f * (hp[0] + hp[D] + hp[2*D] + hp[3*D]);
    vals[i] = m; ss += m*m;
  }
  red[tid] = ss; __syncthreads();
  for (int off = 128; off > 0; off >>= 1) { if (tid < off) red[tid] += red[tid + off]; __syncthreads(); }
  const float inv = 1.f / sqrtf(red[0] * (1.f/(float)D) + 1e-6f);
  #pragma unroll
  for (int i = 0; i < 4; ++i) {
    const int d = tid + i*256;
    xn[(size_t)sb * D + d] = vals[i] * w[d] * inv;
  }
}

// ---------------- decode output PLIF -> spike counts (exact bf16 ints) ----------------
__global__ __launch_bounds__(256)
void dplif_kernel(const float* __restrict__ xn, const float* __restrict__ beta,
                  const float* __restrict__ vth, u16* __restrict__ dec) {
  const int idx = blockIdx.x * 256 + threadIdx.x;
  const int b = idx / D, d = idx % D;
  const float be = beta[d], vt = vth[d], omb = 1.f - be;
  float v = 0.f;
  for (int s = 0; s < S; ++s) {
    const float xv = xn[((size_t)s * B + b) * D + d];
    float cnt = 0.f;
    #pragma unroll
    for (int k = 0; k < KF; ++k) {
      v = fmaf(be, v, omb * xv);
      if (v >= vt) { v -= vt; cnt += 1.f; }
    }
    const __hip_bfloat16 hb_ = __float2bfloat16(cnt);
    dec[((size_t)b * S + s) * D + d] = *(const u16*)&hb_;
  }
}

// ---------------- lateral inhibition (in-place, with bias add) ----------------
__global__ __launch_bounds__(256)
void li_kernel(float* __restrict__ hh, const float* __restrict__ bias,
               const float* __restrict__ w) {
  const int r = blockIdx.x, tid = threadIdx.x;
  __shared__ float red[256];
  float* row = hh + (size_t)r * D;
  float v[4]; float sm = 0.f;
  #pragma unroll
  for (int i = 0; i < 4; ++i) { const int d = tid + i*256; v[i] = row[d] + bias[d]; sm += v[i]; }
  red[tid] = sm; __syncthreads();
  for (int off = 128; off > 0; off >>= 1) { if (tid < off) red[tid] += red[tid + off]; __syncthreads(); }
  const float mean = red[0] * (1.f/(float)D);
  __syncthreads();
  float ss = 0.f;
  #pragma unroll
  for (int i = 0; i < 4; ++i) { v[i] -= mean; ss += v[i]*v[i]; }
  red[tid] = ss; __syncthreads();
  for (int off = 128; off > 0; off >>= 1) { if (tid < off) red[tid] += red[tid + off]; __syncthreads(); }
  const float inv = 1.f / sqrtf(red[0] * (1.f/(float)D) + 1e-6f);
  #pragma unroll
  for (int i = 0; i < 4; ++i) { const int d = tid + i*256; row[d] = w[d] * v[i] * inv; }
}

// ---------------- hi/lo split of a fp32 activation matrix [M][Kd] -> [M][2Kd] ----------------
__global__ __launch_bounds__(256)
void split_kernel(const float* __restrict__ X, u16* __restrict__ xs, int Kd) {
  const size_t idx = (size_t)blockIdx.x * 256 + threadIdx.x;
  const int k = (int)(idx % Kd);
  const size_t n = idx / Kd;
  const float v = X[idx];
  const __hip_bfloat16 h = __float2bfloat16(v);
  const size_t off = n * (2*Kd) + k;
  xs[off] = *(const u16*)&h;
  const __hip_bfloat16 lo = __float2bfloat16(v - __bfloat162float(h));
  xs[off + Kd] = *(const u16*)&lo;
}

// ---------------- ponder / ekf tail ----------------
__global__ void finalize_kernel(const float* __restrict__ ek_acc, float* __restrict__ tail) {
  if (threadIdx.x != 0 || blockIdx.x != 0) return;
  float ponder = 0.f, ekf = 0.f;
  for (int l = 0; l < LNUM; ++l) {
    float ek = ek_acc[l] * (1.f/(float)(S*B));
    ponder += ek;
    ekf += fmaxf(0.f - ek, 0.f);
  }
  tail[0] = ponder * (1.f/(float)LNUM);
  tail[1] = ekf * (1.f/(float)LNUM);
}

extern "C" void kernel_launch(void* const* d_in, const int* in_sizes, int n_in,
                              void* d_out, int out_size, void* d_ws, size_t ws_size,
                              hipStream_t stream) {
  const int*   tok       = (const int*)  d_in[0];
  const float* embed     = (const float*)d_in[1];
  const float* norm_w    = (const float*)d_in[2];
  const float* decode_W  = (const float*)d_in[3];
  const float* decode_b  = (const float*)d_in[4];
  const float* out_norm  = (const float*)d_in[5];
  const float* beta_out  = (const float*)d_in[6];
  const float* vth_out   = (const float*)d_in[7];
  const float* H_logits  = (const float*)d_in[8];
  const float* w_pre     = (const float*)d_in[9];
  const float* w_post    = (const float*)d_in[10];
  const float* beta_in1  = (const float*)d_in[11];
  const float* vth_in1   = (const float*)d_in[12];
  const float* W_in      = (const float*)d_in[13];
  const float* beta_h    = (const float*)d_in[14];
  const float* vth_h     = (const float*)d_in[15];
  const float* W_out     = (const float*)d_in[16];
  const float* beta_in2  = (const float*)d_in[17];
  const float* vth_in2   = (const float*)d_in[18];
  const float* W_gate    = (const float*)d_in[19];
  const float* beta_gate = (const float*)d_in[20];
  const float* vth_gate  = (const float*)d_in[21];
  const float* W_up      = (const float*)d_in[22];
  const float* beta_up   = (const float*)d_in[23];
  const float* vth_up    = (const float*)d_in[24];
  const float* W_down    = (const float*)d_in[25];
  const float* halt_w    = (const float*)d_in[26];
  const float* halt_b    = (const float*)d_in[27];
  float* out = (float*)d_out;

  float* ws = (float*)d_ws;
  size_t o = 0;
  float* prm   = ws + o; o += 256;
  float* h_cur = ws + o; o += (size_t)S*B*NS*D;        // 2.10M f
  float* h_mix = ws + o; o += (size_t)S*B*NS*D;        // 2.10M
  float* xbuf  = ws + o; o += (size_t)S*B*D;           // 0.52M
  float* y_blk = ws + o; o += (size_t)TB*D;            // 4.19M
  float* zbig  = ws + o; o += (size_t)TB*2*DFF;        // 25.2M f: z_h [TB][ND] / z12 [TB][6144] / decode splits
  u16*   spb   = (u16*)(ws + o); o += (size_t)TB*ND/2; // sh spikes / g*u spikes
  u16*   s1b   = (u16*)(ws + o); o += (size_t)TB*D/2;
  u16*   s2b   = (u16*)(ws + o); o += (size_t)TB*D/2;
  float* xn    = ws + o; o += (size_t)S*B*D;
  u16*   decb  = (u16*)(ws + o); o += (size_t)B*S*D/2;
  float* hh    = ws + o; o += (size_t)B*S*D;
  u16*   wt    = (u16*)(ws + o); o += (size_t)(2*DFF)*D;  // up to [6144][2048] u16
  if (ws_size < o * sizeof(float)) return;             // fail loudly (output stays poison/zero)

  float* ek_acc = prm + 96;
  hipMemsetAsync(ek_acc, 0, 3 * sizeof(float), stream);

  gather_kernel<<<(S*B*NS*D)/256, 256, 0, stream>>>(tok, embed, h_cur);

  for (int l = 0; l < LNUM; ++l) {
    float* P = prm + l*32;
    sink_kernel<<<1, 64, 0, stream>>>(H_logits + l*16, w_pre + l*4, w_post + l*4, P);
    mix_kernel<<<(S*B*D)/256, 256, 0, stream>>>(h_cur, P, h_mix, xbuf);
    plif_kernel<true,false><<<(B*D)/256, 256, 0, stream>>>(
        xbuf, nullptr, beta_in1 + l*D, vth_in1 + l*D, s1b, D);

    // z_h = s1 @ W_in (vth_in1 folded): 256^2 kernel, A [TB][1024], B [4096][2048]
    { dim3 gp(ND/64, D/64);
      prep_t_kernel<<<gp, 256, 0, stream>>>(W_in + (size_t)l*D*ND, vth_in1 + l*D, nullptr, 1.f,
                                            wt, D, ND); }
    { dim3 g(ND/256, TB/256);
      mgemm3_kernel<<<g, 512, 0, stream>>>(s1b, wt, zbig, TB, ND, D, D, 2*D); }
    plif_kernel<false,false><<<(B*ND)/256, 256, 0, stream>>>(
        zbig, nullptr, beta_h + l*ND, vth_h + l*ND, spb, ND);

    // y_blk = sh @ W_out (vth_h folded): 128^2 kernel, B [1024][8192]
    { dim3 gp(D/64, ND/64);
      prep_t_kernel<<<gp, 256, 0, stream>>>(W_out + (size_t)l*ND*D, vth_h + l*ND, nullptr, 1.f,
                                            wt, ND, D); }
    { dim3 g(D/128, TB/128);
      mgemm2_kernel<false><<<g, 256, 0, stream>>>(spb, wt, nullptr, y_blk, TB, D,
                                                  ND, ND, 2*ND, 2*ND, 2*ND); }
    plif_kernel<true,true><<<(B*D)/256, 256, 0, stream>>>(
        xbuf, y_blk, beta_in2 + l*D, vth_in2 + l*D, s2b, D);

    // z12 = s2 @ [W_gate | W_up] (vth_in2 folded): 256^2 kernel, B [6144][2048]
    { dim3 gp(DFF/64, D/64);
      prep_t_kernel<<<gp, 256, 0, stream>>>(W_gate + (size_t)l*D*DFF, vth_in2 + l*D, nullptr, 1.f,
                                            wt, D, DFF);
      prep_t_kernel<<<gp, 256, 0, stream>>>(W_up + (size_t)l*D*DFF, vth_in2 + l*D, nullptr, 1.f,
                                            wt + (size_t)DFF*2*D, D, DFF); }
    { dim3 g((2*DFF)/256, TB/256);
      mgemm3_kernel<<<g, 512, 0, stream>>>(s2b, wt, zbig, TB, 2*DFF, D, D, 2*D); }
    plif_gu_kernel<<<(B*DFF)/256, 256, 0, stream>>>(
        zbig, beta_gate + l*DFF, vth_gate + l*DFF, beta_up + l*DFF, vth_up + l*DFF, spb);

    // y += (g*u) @ W_down (vth_g*vth_u folded): 128^2 kernel, B [1024][6144]
    { dim3 gp(D/64, DFF/64);
      prep_t_kernel<<<gp, 256, 0, stream>>>(W_down + (size_t)l*DFF*D, vth_gate + l*DFF,
                                            vth_up + l*DFF, 1.f, wt, DFF, D); }
    { dim3 g(D/128, TB/128);
      mgemm2_kernel<true><<<g, 256, 0, stream>>>(spb, wt, y_blk, y_blk, TB, D,
                                                 DFF, DFF, 2*DFF, 2*DFF, 2*DFF); }
    halt_kernel<<<S*B, 256, 0, stream>>>(y_blk, h_mix, P, halt_w + l*D, halt_b + l, h_cur, ek_acc + l);
  }

  collnorm_kernel<<<S*B, 256, 0, stream>>>(h_cur, out_norm, xn);
  dplif_kernel<<<(B*D)/256, 256, 0, stream>>>(xn, beta_out, vth_out, decb);

  // hh = dec @ (decode_W * vth_out/8)^T: 128^2 kernel
  prep_nt_kernel<<<(D*D)/256, 256, 0, stream>>>(decode_W, vth_out, 0.125f, wt, D);
  { dim3 g(D/128, (B*S)/128);
    mgemm2_kernel<false><<<g, 256, 0, stream>>>(decb, wt, nullptr, hh, B*S, D,
                                                D, D, 2*D, 2*D, 2*D); }
  li_kernel<<<B*S, 256, 0, stream>>>(hh, decode_b, norm_w);

  // logits = hh @ embed^T, 3-term split: K2=3D loop over B [6144][2048] (Bstride=2D)
  u16* hh_c  = (u16*)(zbig + 6600000);
  u16* emb_c = (u16*)zbig;
  split_kernel<<<(B*S*D)/256, 256, 0, stream>>>(hh, hh_c, D);
  prep_nt_kernel<<<(VOCABSZ*D)/256, 256, 0, stream>>>(embed, nullptr, 1.f, emb_c, D);
  { dim3 g(VOCABSZ/128, (B*S)/128);
    mgemm2_kernel<false><<<g, 256, 0, stream>>>(hh_c, emb_c, nullptr, out, B*S, VOCABSZ,
                                                2*D, D, 2*D, 2*D, 3*D); }
  finalize_kernel<<<1, 1, 0, stream>>>(ek_acc, out + (out_size - 2));
}

// Round 7
// 2488.941 us; speedup vs baseline: 2.9917x; 1.0224x over previous
//
#include <hip/hip_runtime.h>
#include <hip/hip_bf16.h>

#define B 4
#define S 128
#define D 1024
#define NS 4
#define KF 8
#define LNUM 3
#define DFF 3072
#define ND 4096
#define T 1024          // S*KF
#define TB 4096         // T*B
#define VOCABSZ 6144
#define SINKIT 20

typedef unsigned short u16;
typedef __attribute__((ext_vector_type(8))) short short8;
typedef __attribute__((ext_vector_type(4))) float f32x4;

__device__ __forceinline__ void gload16(const void* g, void* l) {
  __builtin_amdgcn_global_load_lds(
      (const __attribute__((address_space(1))) void*)g,
      (__attribute__((address_space(3))) void*)l, 16, 0, 0);
}

// ---------------- sinkhorn + softmax(w_pre/w_post) ----------------
__global__ void sink_kernel(const float* __restrict__ Hl, const float* __restrict__ wpre,
                            const float* __restrict__ wpost, float* __restrict__ prm) {
  if (threadIdx.x != 0 || blockIdx.x != 0) return;
  float M[16];
  for (int i = 0; i < 16; ++i) M[i] = expf(Hl[i]);
  for (int it = 0; it < SINKIT; ++it) {
    for (int m = 0; m < 4; ++m) {
      float s = M[m*4+0] + M[m*4+1] + M[m*4+2] + M[m*4+3];
      for (int n = 0; n < 4; ++n) M[m*4+n] /= s;
    }
    for (int n = 0; n < 4; ++n) {
      float s = M[0*4+n] + M[1*4+n] + M[2*4+n] + M[3*4+n];
      for (int m = 0; m < 4; ++m) M[m*4+n] /= s;
    }
  }
  for (int i = 0; i < 16; ++i) prm[i] = M[i];
  float a[4], mx, sm;
  mx = fmaxf(fmaxf(wpre[0], wpre[1]), fmaxf(wpre[2], wpre[3]));
  sm = 0.f; for (int i = 0; i < 4; ++i) { a[i] = expf(wpre[i] - mx); sm += a[i]; }
  for (int i = 0; i < 4; ++i) prm[16+i] = a[i] / sm;
  mx = fmaxf(fmaxf(wpost[0], wpost[1]), fmaxf(wpost[2], wpost[3]));
  sm = 0.f; for (int i = 0; i < 4; ++i) { a[i] = expf(wpost[i] - mx); sm += a[i]; }
  for (int i = 0; i < 4; ++i) prm[20+i] = a[i] / sm;
}

// ---------------- embed gather ----------------
__global__ __launch_bounds__(256)
void gather_kernel(const int* __restrict__ tok, const float* __restrict__ embed,
                   float* __restrict__ h) {
  const int idx = blockIdx.x * 256 + threadIdx.x;
  const int d   = idx % D;
  const int sbn = idx / D;
  const int sb  = sbn / NS;
  const int b   = sb % B, s = sb / B;
  h[idx] = embed[(size_t)tok[b*S + s] * D + d];
}

// ---------------- stream mix ----------------
__global__ __launch_bounds__(256)
void mix_kernel(const float* __restrict__ h, const float* __restrict__ P,
                float* __restrict__ h_mix, float* __restrict__ x) {
  const int idx = blockIdx.x * 256 + threadIdx.x;
  const int d = idx % D, sb = idx / D;
  const float* hp = h + (size_t)sb * NS * D + d;
  const float h0 = hp[0], h1 = hp[D], h2 = hp[2*D], h3 = hp[3*D];
  float xv = 0.f;
  #pragma unroll
  for (int m = 0; m < 4; ++m) {
    float hm = P[m*4+0]*h0 + P[m*4+1]*h1 + P[m*4+2]*h2 + P[m*4+3]*h3;
    h_mix[(size_t)sb * NS * D + m*D + d] = hm;
    xv = fmaf(P[16+m], hm, xv);
  }
  x[idx] = xv;
}

// ---------------- PLIF scan -> binary bf16 spikes ----------------
template<bool R1, bool A2>
__global__ __launch_bounds__(256)
void plif_kernel(const float* __restrict__ z1, const float* __restrict__ z2,
                 const float* __restrict__ beta, const float* __restrict__ vth,
                 u16* __restrict__ outp, int C) {
  const int idx = blockIdx.x * 256 + threadIdx.x;
  const int c = idx % C;
  const int stride = B * C;
  const float be = beta[c], vt = vth[c], omb = 1.f - be;
  float v = 0.f;
  #pragma unroll 16
  for (int t = 0; t < T; ++t) {
    float xt = R1 ? z1[(size_t)(t >> 3) * stride + idx] : z1[(size_t)t * stride + idx];
    if (A2) xt += z2[(size_t)t * stride + idx];
    v = fmaf(be, v, omb * xt);
    const bool sp = (v >= vt);
    if (sp) v -= vt;
    outp[(size_t)t * stride + idx] = sp ? (u16)0x3F80 : (u16)0;
  }
}

// ---------------- fused gate+up PLIF from fused z12 [t][b][6144] ----------------
__global__ __launch_bounds__(256)
void plif_gu_kernel(const float* __restrict__ z12,
                    const float* __restrict__ bg, const float* __restrict__ vg_,
                    const float* __restrict__ bu, const float* __restrict__ vu_,
                    u16* __restrict__ outp) {
  const int idx = blockIdx.x * 256 + threadIdx.x;   // over B*DFF
  const int c = idx % DFF, b = idx / DFF;
  const float beg = bg[c], vtg = vg_[c], beu = bu[c], vtu = vu_[c];
  const float og = 1.f - beg, ou = 1.f - beu;
  float vg = 0.f, vu = 0.f;
  #pragma unroll 16
  for (int t = 0; t < T; ++t) {
    const size_t off = ((size_t)t * B + b) * (2*DFF) + c;
    vg = fmaf(beg, vg, og * z12[off]);
    vu = fmaf(beu, vu, ou * z12[off + DFF]);
    const bool sg = (vg >= vtg), su = (vu >= vtu);
    if (sg) vg -= vtg;
    if (su) vu -= vtu;
    outp[(size_t)t * (B*DFF) + idx] = (sg && su) ? (u16)0x3F80 : (u16)0;
  }
}

// ---------------- weight prep: transpose + scale + bf16 hi/lo split -> [N][2K] ----------------
__global__ __launch_bounds__(256)
void prep_t_kernel(const float* __restrict__ W, const float* __restrict__ sA,
                   const float* __restrict__ sB, float mult,
                   u16* __restrict__ wt, int Kd, int Nd) {
  __shared__ float tile[64][65];
  const int tid = threadIdx.x;
  const int bn = blockIdx.x, bk = blockIdx.y;
  const int c = tid & 63, r0 = (tid >> 6) * 16;
  #pragma unroll
  for (int i = 0; i < 16; ++i) {
    const int r = r0 + i;
    const int kg = bk*64 + r;
    float s = mult;
    if (sA) s *= sA[kg];
    if (sB) s *= sB[kg];
    tile[r][c] = W[(size_t)kg * Nd + bn*64 + c] * s;
  }
  __syncthreads();
  const int K2 = 2 * Kd;
  #pragma unroll
  for (int i = 0; i < 16; ++i) {
    const int nl = r0 + i;
    const float v = tile[c][nl];
    const __hip_bfloat16 h = __float2bfloat16(v);
    const size_t off = (size_t)(bn*64 + nl) * K2 + bk*64 + c;
    wt[off] = *(const u16*)&h;
    const __hip_bfloat16 lo = __float2bfloat16(v - __bfloat162float(h));
    wt[off + Kd] = *(const u16*)&lo;
  }
}

// ---------------- prep (no transpose): W [Nd][Kd] -> wt [Nd][2Kd] hi|lo ----------------
__global__ __launch_bounds__(256)
void prep_nt_kernel(const float* __restrict__ W, const float* __restrict__ sK, float mult,
                    u16* __restrict__ wt, int Kd) {
  const size_t idx = (size_t)blockIdx.x * 256 + threadIdx.x;
  const int k = (int)(idx % Kd);
  const size_t n = idx / Kd;
  const float v = W[idx] * mult * (sK ? sK[k] : 1.f);
  const __hip_bfloat16 h = __float2bfloat16(v);
  const size_t off = n * (2*Kd) + k;
  wt[off] = *(const u16*)&h;
  const __hip_bfloat16 lo = __float2bfloat16(v - __bfloat162float(h));
  wt[off + Kd] = *(const u16*)&lo;
}

// Swizzle scheme (both GEMMs, rule #21 both-sides):
//  LDS row = 64B = 4 chunks of 16B. LDS stays LINEAR for global_load_lds;
//  the global SOURCE chunk is permuted: csrc = chunk ^ ((row>>1)&3).
//  Reader wanting k-chunk ks of row r reads slot (ks ^ ((r>>1)&3)).
//  Bank math: start = 16*(lr&1) + 4*slot -> each 4-bank group gets exactly 2
//  of the 16 lanes per ks-group (2-way = free, m136).

// ---------------- 128x128 bf16 MFMA GEMM ----------------
template<bool ADDC>
__global__ __launch_bounds__(256)
void mgemm2_kernel(const u16* __restrict__ A, const u16* __restrict__ Bm,
                   const float* __restrict__ Cin, float* __restrict__ Cout,
                   int M, int N, int Astride, int AW, int BW, int Bstride, int K2) {
  __shared__ __align__(16) char lds[32768];
  const int tid = threadIdx.x;
  const int lane = tid & 63, wv = tid >> 6;
  const int wm = wv >> 1, wn = wv & 1;
  const int lr = lane & 15, ks = lane >> 4;
  const int rs3 = (lr >> 1) & 3;               // read-side row swizzle key

  const int gx = gridDim.x;
  const int nwg = gx * gridDim.y;
  int flat = blockIdx.y * gx + blockIdx.x;
  flat = (flat & 7) * (nwg >> 3) + (flat >> 3);
  const int bn = flat % gx, bm = flat / gx;

  f32x4 acc[4][4];
  #pragma unroll
  for (int i = 0; i < 4; ++i)
    #pragma unroll
    for (int j = 0; j < 4; ++j) acc[i][j] = (f32x4){0.f, 0.f, 0.f, 0.f};

  const size_t am0 = (size_t)bm * 128, bn0 = (size_t)bn * 128;

#define STAGE(bufbase, k0) do {                                                  \
    const int aoff_ = ((k0) >= AW) ? (k0) - AW : (k0);                           \
    const int boff_ = ((k0) >= BW) ? (k0) - BW : (k0);                           \
    _Pragma("unroll")                                                            \
    for (int c_ = 0; c_ < 2; ++c_) {                                             \
      const int bo_ = c_*4096 + wv*1024 + lane*16;                               \
      const int row_ = bo_ >> 6;                                                 \
      const int csrc_ = ((bo_ >> 4) & 3) ^ ((row_ >> 1) & 3);                    \
      gload16((const char*)A + ((am0 + row_) * (size_t)Astride + aoff_ + csrc_*8) * 2, \
              lds + (bufbase) + c_*4096 + wv*1024);                              \
      gload16((const char*)Bm + ((bn0 + row_) * (size_t)Bstride + boff_ + csrc_*8) * 2, \
              lds + (bufbase) + 8192 + c_*4096 + wv*1024);                       \
    }                                                                            \
  } while (0)

  const int nt = K2 >> 5;
  STAGE(0, 0);
  __syncthreads();
  int cur = 0;
  for (int t = 0; t < nt; ++t) {
    if (t + 1 < nt) STAGE((cur ^ 1) * 16384, (t + 1) << 5);
    const char* la = lds + cur * 16384;
    const char* lb = la + 8192;
    short8 af[4], bf[4];
    #pragma unroll
    for (int f = 0; f < 4; ++f) {
      af[f] = *(const short8*)(la + (wm*64 + f*16 + lr)*64 + ((ks ^ rs3) * 16));
      bf[f] = *(const short8*)(lb + (wn*64 + f*16 + lr)*64 + ((ks ^ rs3) * 16));
    }
    #pragma unroll
    for (int i = 0; i < 4; ++i)
      #pragma unroll
      for (int j = 0; j < 4; ++j)
        acc[i][j] = __builtin_amdgcn_mfma_f32_16x16x32_bf16(af[i], bf[j], acc[i][j], 0, 0, 0);
    __syncthreads();
    cur ^= 1;
  }
#undef STAGE

  const int col0 = bn*128 + wn*64 + lr;
  #pragma unroll
  for (int i = 0; i < 4; ++i)
    #pragma unroll
    for (int j = 0; j < 4; ++j) {
      const size_t rbase = (size_t)(bm*128 + wm*64 + i*16 + ks*4);
      #pragma unroll
      for (int r = 0; r < 4; ++r) {
        const size_t idx = (rbase + r) * (size_t)N + col0 + j*16;
        float v = acc[i][j][r];
        if (ADDC) v += Cin[idx];
        Cout[idx] = v;
      }
    }
}

// ---------------- 256x256 bf16 MFMA GEMM: counted-vmcnt 2-barrier, swizzled LDS ----
__global__ __launch_bounds__(512)
void mgemm3_kernel(const u16* __restrict__ A, const u16* __restrict__ Bm,
                   float* __restrict__ Cout, int M, int N, int Astride, int AW, int K2) {
  __shared__ __align__(16) char lds[65536];   // [buf: A 16K | B 16K] x2
  const int tid = threadIdx.x;
  const int lane = tid & 63, wv = tid >> 6;
  const int wm = wv >> 2, wn = wv & 3;
  const int lr = lane & 15, ks = lane >> 4;
  const int rs3 = (lr >> 1) & 3;               // read-side row swizzle key

  const int gx = gridDim.x;
  const int nwg = gx * gridDim.y;
  int flat = blockIdx.y * gx + blockIdx.x;
  flat = (flat & 7) * (nwg >> 3) + (flat >> 3);
  const int bn = flat % gx, bm = flat / gx;

  f32x4 acc[8][4];
  #pragma unroll
  for (int i = 0; i < 8; ++i)
    #pragma unroll
    for (int j = 0; j < 4; ++j) acc[i][j] = (f32x4){0.f, 0.f, 0.f, 0.f};

  const size_t am0 = (size_t)bm * 256, bn0 = (size_t)bn * 256;

#define STG(base, k0) do {                                                        \
    const int aoff_ = ((k0) >= AW) ? (k0) - AW : (k0);                            \
    _Pragma("unroll")                                                             \
    for (int c_ = 0; c_ < 2; ++c_) {                                              \
      const int fl_ = c_*8192 + wv*1024 + lane*16;                                \
      const int row_ = fl_ >> 6;                                                  \
      const int csrc_ = ((fl_ >> 4) & 3) ^ ((row_ >> 1) & 3);                     \
      gload16((const char*)A + ((am0 + row_) * (size_t)Astride + aoff_ + csrc_*8) * 2, \
              lds + (base) + c_*8192 + wv*1024);                                  \
      gload16((const char*)Bm + ((bn0 + row_) * (size_t)K2 + (k0) + csrc_*8) * 2, \
              lds + (base) + 16384 + c_*8192 + wv*1024);                          \
    }                                                                             \
  } while (0)

  const int nt = K2 >> 5;
  STG(0, 0);
  for (int t = 0; t < nt; ++t) {
    // barrier A: everyone finished computing from this buffer's previous tile
    asm volatile("s_barrier" ::: "memory");
    if (t + 1 < nt) {
      STG(((t + 1) & 1) * 32768, (t + 1) << 5);
      // wait own stage(t) (4 newest = stage(t+1) stay in flight), then join
      asm volatile("s_waitcnt vmcnt(4)\n\ts_barrier" ::: "memory");
    } else {
      asm volatile("s_waitcnt vmcnt(0)\n\ts_barrier" ::: "memory");
    }
    const char* la = lds + (t & 1) * 32768;
    const char* lb = la + 16384;
    short8 af[8], bf[4];
    #pragma unroll
    for (int i = 0; i < 8; ++i)
      af[i] = *(const short8*)(la + (wm*128 + i*16 + lr)*64 + ((ks ^ rs3) * 16));
    #pragma unroll
    for (int j = 0; j < 4; ++j)
      bf[j] = *(const short8*)(lb + (wn*64 + j*16 + lr)*64 + ((ks ^ rs3) * 16));
    #pragma unroll
    for (int i = 0; i < 8; ++i)
      #pragma unroll
      for (int j = 0; j < 4; ++j)
        acc[i][j] = __builtin_amdgcn_mfma_f32_16x16x32_bf16(af[i], bf[j], acc[i][j], 0, 0, 0);
  }
#undef STG

  const int col0 = bn*256 + wn*64 + lr;
  #pragma unroll
  for (int i = 0; i < 8; ++i)
    #pragma unroll
    for (int j = 0; j < 4; ++j) {
      const size_t rbase = (size_t)(bm*256 + wm*128 + i*16 + ks*4);
      #pragma unroll
      for (int r = 0; r < 4; ++r)
        Cout[(rbase + r) * (size_t)N + col0 + j*16] = acc[i][j][r];
    }
}

// ---------------- PonderNet halting + stream write-back ----------------
__global__ __launch_bounds__(256)
void halt_kernel(const float* __restrict__ y, const float* __restrict__ h_mix,
                 const float* __restrict__ P, const float* __restrict__ hw,
                 const float* __restrict__ hb, float* __restrict__ h_out,
                 float* __restrict__ ek_acc) {
  const int sb = blockIdx.x;
  const int b = sb % B, s = sb / B;
  const int tid = threadIdx.x;
  __shared__ float red[256];
  __shared__ float lam_s[KF];
  __shared__ float pk_s[KF];

  for (int k = 0; k < KF; ++k) {
    const float* yr = y + ((size_t)(s*KF + k) * B + b) * D;
    float p = 0.f;
    for (int d = tid; d < D; d += 256) p = fmaf(yr[d], hw[d], p);
    red[tid] = p; __syncthreads();
    for (int off = 128; off > 0; off >>= 1) {
      if (tid < off) red[tid] += red[tid + off];
      __syncthreads();
    }
    if (tid == 0) lam_s[k] = 1.f / (1.f + expf(-(red[0] + hb[0])));
    __syncthreads();
  }
  if (tid == 0) {
    float keep = 1.f, sum = 0.f, pk[KF];
    #pragma unroll
    for (int k = 0; k < KF; ++k) { pk[k] = lam_s[k] * keep; keep *= (1.f - lam_s[k]); sum += pk[k]; }
    pk[KF-1] += 1.f - sum;
    float ek = 0.f;
    #pragma unroll
    for (int k = 0; k < KF; ++k) { ek += pk[k] * (float)(k + 1); pk_s[k] = pk[k]; }
    atomicAdd(ek_acc, ek);
  }
  __syncthreads();
  for (int d = tid; d < D; d += 256) {
    float yt = 0.f;
    #pragma unroll
    for (int k = 0; k < KF; ++k)
      yt = fmaf(pk_s[k], y[((size_t)(s*KF + k) * B + b) * D + d], yt);
    #pragma unroll
    for (int n = 0; n < NS; ++n) {
      const size_t off = ((size_t)sb * NS + n) * D + d;
      h_out[off] = h_mix[off] + P[20+n] * yt;
    }
  }
}

// ---------------- decode: stream-collapse + rmsnorm ----------------
__global__ __launch_bounds__(256)
void collnorm_kernel(const float* __restrict__ h, const float* __restrict__ w,
                     float* __restrict__ xn) {
  const int sb = blockIdx.x, tid = threadIdx.x;
  __shared__ float red[256];
  float vals[4]; float ss = 0.f;
  #pragma unroll
  for (int i = 0; i < 4; ++i) {
    const int d = tid + i*256;
    const float* hp = h + (size_t)sb * NS * D + d;
    float m = 0.25f * (hp[0] + hp[D] + hp[2*D] + hp[3*D]);
    vals[i] = m; ss += m*m;
  }
  red[tid] = ss; __syncthreads();
  for (int off = 128; off > 0; off >>= 1) { if (tid < off) red[tid] += red[tid + off]; __syncthreads(); }
  const float inv = 1.f / sqrtf(red[0] * (1.f/(float)D) + 1e-6f);
  #pragma unroll
  for (int i = 0; i < 4; ++i) {
    const int d = tid + i*256;
    xn[(size_t)sb * D + d] = vals[i] * w[d] * inv;
  }
}

// ---------------- decode output PLIF -> spike counts (exact bf16 ints) ----------------
__global__ __launch_bounds__(256)
void dplif_kernel(const float* __restrict__ xn, const float* __restrict__ beta,
                  const float* __restrict__ vth, u16* __restrict__ dec) {
  const int idx = blockIdx.x * 256 + threadIdx.x;
  const int b = idx / D, d = idx % D;
  const float be = beta[d], vt = vth[d], omb = 1.f - be;
  float v = 0.f;
  for (int s = 0; s < S; ++s) {
    const float xv = xn[((size_t)s * B + b) * D + d];
    float cnt = 0.f;
    #pragma unroll
    for (int k = 0; k < KF; ++k) {
      v = fmaf(be, v, omb * xv);
      if (v >= vt) { v -= vt; cnt += 1.f; }
    }
    const __hip_bfloat16 hb_ = __float2bfloat16(cnt);
    dec[((size_t)b * S + s) * D + d] = *(const u16*)&hb_;
  }
}

// ---------------- lateral inhibition (in-place, with bias add) ----------------
__global__ __launch_bounds__(256)
void li_kernel(float* __restrict__ hh, const float* __restrict__ bias,
               const float* __restrict__ w) {
  const int r = blockIdx.x, tid = threadIdx.x;
  __shared__ float red[256];
  float* row = hh + (size_t)r * D;
  float v[4]; float sm = 0.f;
  #pragma unroll
  for (int i = 0; i < 4; ++i) { const int d = tid + i*256; v[i] = row[d] + bias[d]; sm += v[i]; }
  red[tid] = sm; __syncthreads();
  for (int off = 128; off > 0; off >>= 1) { if (tid < off) red[tid] += red[tid + off]; __syncthreads(); }
  const float mean = red[0] * (1.f/(float)D);
  __syncthreads();
  float ss = 0.f;
  #pragma unroll
  for (int i = 0; i < 4; ++i) { v[i] -= mean; ss += v[i]*v[i]; }
  red[tid] = ss; __syncthreads();
  for (int off = 128; off > 0; off >>= 1) { if (tid < off) red[tid] += red[tid + off]; __syncthreads(); }
  const float inv = 1.f / sqrtf(red[0] * (1.f/(float)D) + 1e-6f);
  #pragma unroll
  for (int i = 0; i < 4; ++i) { const int d = tid + i*256; row[d] = w[d] * v[i] * inv; }
}

// ---------------- hi/lo split of a fp32 activation matrix [M][Kd] -> [M][2Kd] ----------------
__global__ __launch_bounds__(256)
void split_kernel(const float* __restrict__ X, u16* __restrict__ xs, int Kd) {
  const size_t idx = (size_t)blockIdx.x * 256 + threadIdx.x;
  const int k = (int)(idx % Kd);
  const size_t n = idx / Kd;
  const float v = X[idx];
  const __hip_bfloat16 h = __float2bfloat16(v);
  const size_t off = n * (2*Kd) + k;
  xs[off] = *(const u16*)&h;
  const __hip_bfloat16 lo = __float2bfloat16(v - __bfloat162float(h));
  xs[off + Kd] = *(const u16*)&lo;
}

// ---------------- ponder / ekf tail ----------------
__global__ void finalize_kernel(const float* __restrict__ ek_acc, float* __restrict__ tail) {
  if (threadIdx.x != 0 || blockIdx.x != 0) return;
  float ponder = 0.f, ekf = 0.f;
  for (int l = 0; l < LNUM; ++l) {
    float ek = ek_acc[l] * (1.f/(float)(S*B));
    ponder += ek;
    ekf += fmaxf(0.f - ek, 0.f);
  }
  tail[0] = ponder * (1.f/(float)LNUM);
  tail[1] = ekf * (1.f/(float)LNUM);
}

extern "C" void kernel_launch(void* const* d_in, const int* in_sizes, int n_in,
                              void* d_out, int out_size, void* d_ws, size_t ws_size,
                              hipStream_t stream) {
  const int*   tok       = (const int*)  d_in[0];
  const float* embed     = (const float*)d_in[1];
  const float* norm_w    = (const float*)d_in[2];
  const float* decode_W  = (const float*)d_in[3];
  const float* decode_b  = (const float*)d_in[4];
  const float* out_norm  = (const float*)d_in[5];
  const float* beta_out  = (const float*)d_in[6];
  const float* vth_out   = (const float*)d_in[7];
  const float* H_logits  = (const float*)d_in[8];
  const float* w_pre     = (const float*)d_in[9];
  const float* w_post    = (const float*)d_in[10];
  const float* beta_in1  = (const float*)d_in[11];
  const float* vth_in1   = (const float*)d_in[12];
  const float* W_in      = (const float*)d_in[13];
  const float* beta_h    = (const float*)d_in[14];
  const float* vth_h     = (const float*)d_in[15];
  const float* W_out     = (const float*)d_in[16];
  const float* beta_in2  = (const float*)d_in[17];
  const float* vth_in2   = (const float*)d_in[18];
  const float* W_gate    = (const float*)d_in[19];
  const float* beta_gate = (const float*)d_in[20];
  const float* vth_gate  = (const float*)d_in[21];
  const float* W_up      = (const float*)d_in[22];
  const float* beta_up   = (const float*)d_in[23];
  const float* vth_up    = (const float*)d_in[24];
  const float* W_down    = (const float*)d_in[25];
  const float* halt_w    = (const float*)d_in[26];
  const float* halt_b    = (const float*)d_in[27];
  float* out = (float*)d_out;

  float* ws = (float*)d_ws;
  size_t o = 0;
  float* prm   = ws + o; o += 256;
  float* h_cur = ws + o; o += (size_t)S*B*NS*D;        // 2.10M f
  float* h_mix = ws + o; o += (size_t)S*B*NS*D;        // 2.10M
  float* xbuf  = ws + o; o += (size_t)S*B*D;           // 0.52M
  float* y_blk = ws + o; o += (size_t)TB*D;            // 4.19M
  float* zbig  = ws + o; o += (size_t)TB*2*DFF;        // 25.2M f: z_h [TB][ND] / z12 [TB][6144] / decode splits
  u16*   spb   = (u16*)(ws + o); o += (size_t)TB*ND/2; // sh spikes / g*u spikes
  u16*   s1b   = (u16*)(ws + o); o += (size_t)TB*D/2;
  u16*   s2b   = (u16*)(ws + o); o += (size_t)TB*D/2;
  float* xn    = ws + o; o += (size_t)S*B*D;
  u16*   decb  = (u16*)(ws + o); o += (size_t)B*S*D/2;
  float* hh    = ws + o; o += (size_t)B*S*D;
  u16*   wt    = (u16*)(ws + o); o += (size_t)(2*DFF)*D;  // up to [6144][2048] u16
  if (ws_size < o * sizeof(float)) return;             // fail loudly (output stays poison/zero)

  float* ek_acc = prm + 96;
  hipMemsetAsync(ek_acc, 0, 3 * sizeof(float), stream);

  gather_kernel<<<(S*B*NS*D)/256, 256, 0, stream>>>(tok, embed, h_cur);

  for (int l = 0; l < LNUM; ++l) {
    float* P = prm + l*32;
    sink_kernel<<<1, 64, 0, stream>>>(H_logits + l*16, w_pre + l*4, w_post + l*4, P);
    mix_kernel<<<(S*B*D)/256, 256, 0, stream>>>(h_cur, P, h_mix, xbuf);
    plif_kernel<true,false><<<(B*D)/256, 256, 0, stream>>>(
        xbuf, nullptr, beta_in1 + l*D, vth_in1 + l*D, s1b, D);

    // z_h = s1 @ W_in (vth_in1 folded): 256^2 kernel, A [TB][1024], B [4096][2048]
    { dim3 gp(ND/64, D/64);
      prep_t_kernel<<<gp, 256, 0, stream>>>(W_in + (size_t)l*D*ND, vth_in1 + l*D, nullptr, 1.f,
                                            wt, D, ND); }
    { dim3 g(ND/256, TB/256);
      mgemm3_kernel<<<g, 512, 0, stream>>>(s1b, wt, zbig, TB, ND, D, D, 2*D); }
    plif_kernel<false,false><<<(B*ND)/256, 256, 0, stream>>>(
        zbig, nullptr, beta_h + l*ND, vth_h + l*ND, spb, ND);

    // y_blk = sh @ W_out (vth_h folded): 128^2 kernel, B [1024][8192]
    { dim3 gp(D/64, ND/64);
      prep_t_kernel<<<gp, 256, 0, stream>>>(W_out + (size_t)l*ND*D, vth_h + l*ND, nullptr, 1.f,
                                            wt, ND, D); }
    { dim3 g(D/128, TB/128);
      mgemm2_kernel<false><<<g, 256, 0, stream>>>(spb, wt, nullptr, y_blk, TB, D,
                                                  ND, ND, 2*ND, 2*ND, 2*ND); }
    plif_kernel<true,true><<<(B*D)/256, 256, 0, stream>>>(
        xbuf, y_blk, beta_in2 + l*D, vth_in2 + l*D, s2b, D);

    // z12 = s2 @ [W_gate | W_up] (vth_in2 folded): 256^2 kernel, B [6144][2048]
    { dim3 gp(DFF/64, D/64);
      prep_t_kernel<<<gp, 256, 0, stream>>>(W_gate + (size_t)l*D*DFF, vth_in2 + l*D, nullptr, 1.f,
                                            wt, D, DFF);
      prep_t_kernel<<<gp, 256, 0, stream>>>(W_up + (size_t)l*D*DFF, vth_in2 + l*D, nullptr, 1.f,
                                            wt + (size_t)DFF*2*D, D, DFF); }
    { dim3 g((2*DFF)/256, TB/256);
      mgemm3_kernel<<<g, 512, 0, stream>>>(s2b, wt, zbig, TB, 2*DFF, D, D, 2*D); }
    plif_gu_kernel<<<(B*DFF)/256, 256, 0, stream>>>(
        zbig, beta_gate + l*DFF, vth_gate + l*DFF, beta_up + l*DFF, vth_up + l*DFF, spb);

    // y += (g*u) @ W_down (vth_g*vth_u folded): 128^2 kernel, B [1024][6144]
    { dim3 gp(D/64, DFF/64);
      prep_t_kernel<<<gp, 256, 0, stream>>>(W_down + (size_t)l*DFF*D, vth_gate + l*DFF,
                                            vth_up + l*DFF, 1.f, wt, DFF, D); }
    { dim3 g(D/128, TB/128);
      mgemm2_kernel<true><<<g, 256, 0, stream>>>(spb, wt, y_blk, y_blk, TB, D,
                                                 DFF, DFF, 2*DFF, 2*DFF, 2*DFF); }
    halt_kernel<<<S*B, 256, 0, stream>>>(y_blk, h_mix, P, halt_w + l*D, halt_b + l, h_cur, ek_acc + l);
  }

  collnorm_kernel<<<S*B, 256, 0, stream>>>(h_cur, out_norm, xn);
  dplif_kernel<<<(B*D)/256, 256, 0, stream>>>(xn, beta_out, vth_out, decb);

  // hh = dec @ (decode_W * vth_out/8)^T: 128^2 kernel
  prep_nt_kernel<<<(D*D)/256, 256, 0, stream>>>(decode_W, vth_out, 0.125f, wt, D);
  { dim3 g(D/128, (B*S)/128);
    mgemm2_kernel<false><<<g, 256, 0, stream>>>(decb, wt, nullptr, hh, B*S, D,
                                                D, D, 2*D, 2*D, 2*D); }
  li_kernel<<<B*S, 256, 0, stream>>>(hh, decode_b, norm_w);

  // logits = hh @ embed^T, 3-term split: K2=3D loop over B [6144][2048] (Bstride=2D)
  u16* hh_c  = (u16*)(zbig + 6600000);
  u16* emb_c = (u16*)zbig;
  split_kernel<<<(B*S*D)/256, 256, 0, stream>>>(hh, hh_c, D);
  prep_nt_kernel<<<(VOCABSZ*D)/256, 256, 0, stream>>>(embed, nullptr, 1.f, emb_c, D);
  { dim3 g(VOCABSZ/128, (B*S)/128);
    mgemm2_kernel<false><<<g, 256, 0, stream>>>(hh_c, emb_c, nullptr, out, B*S, VOCABSZ,
                                                2*D, D, 2*D, 2*D, 3*D); }
  finalize_kernel<<<1, 1, 0, stream>>>(ek_acc, out + (out_size - 2));
}